// Round 2
// 13757.181 us; speedup vs baseline: 1.0672x; 1.0672x over previous
//
#include <hip/hip_runtime.h>
#include <hip/hip_cooperative_groups.h>
#include <hip/hip_fp16.h>

namespace cg = cooperative_groups;

#define TSTEP 128
#define LATD 256

// ---------------------------------------------------------------------------
// R9 (resubmit; prior run died to container-acquire flake, no GPU verdict).
// fp16-resident weights. rocprof R8 showed FETCH_SIZE == full fp32 weight
// set (57.6 MB) refetched EVERY step: per-XCD weight working set 7.3 MB > 4 MB
// XCD L2 -> thrash, latency-limited ~680 GB/s refill dominates phase time
// (VALUBusy 13.5%, HBM 8%, all idle). Fix: all 7 loop weight matrices stored
// fp16 in ws (halves bytes AND drops per-XCD footprint to 3.65 MB < 4 MB ->
// L2-resident across all 128 steps; block->tile map is stable in the
// persistent kernel). fp16->fp32 conversion at LDS-staging time only; hot
// inner loops, LDS layout, phases, and fence-free barrier are unchanged.
// Acts/partials remain fp32 sc1 (isolate this change).
// Folds (verified R3-R8): Wvoih=(Wv@Wo)@Wih0, bfold=(bv@Wo+bo)@Wih0+bih0,
// WhW1=Wh@w1, bhw1=bh@w1+b1. Step = 8 phases.
// ---------------------------------------------------------------------------

struct P {
  const float *z, *w1, *b1, *w2, *b2, *Wv, *bv, *Wo, *bo;
  const float *Wih0, *Whh0, *bih0, *bhh0, *Wih1, *Whh1, *bih1, *bhh1, *Wh, *bh;
  float *out;
  __half *Wvoihh, *Whh0h, *Wih1h, *Whh1h, *WhW1h, *Whh, *w2h;
  float *part, *gin, *h1, *h2, *t1, *bvo, *bfold, *bhw1;
  unsigned *bar;   // leaves at i*32 (i<16), root at 512, flag at 544
};

__device__ __forceinline__ float ald(const float* p) {
  return __hip_atomic_load((float*)p, __ATOMIC_RELAXED, __HIP_MEMORY_SCOPE_AGENT);
}
__device__ __forceinline__ void ast(float* p, float v) {
  __hip_atomic_store(p, v, __ATOMIC_RELAXED, __HIP_MEMORY_SCOPE_AGENT);
}
__device__ __forceinline__ unsigned long long ald64(const unsigned long long* p) {
  return __hip_atomic_load((unsigned long long*)p, __ATOMIC_RELAXED,
                           __HIP_MEMORY_SCOPE_AGENT);
}

// 4 packed halves -> float4 (used only in staging, once per chunk).
__device__ __forceinline__ float4 h4f(unsigned long long u) {
  union { unsigned long long q; __half h[4]; } c; c.q = u;
  return make_float4(__half2float(c.h[0]), __half2float(c.h[1]),
                     __half2float(c.h[2]), __half2float(c.h[3]));
}
__device__ __forceinline__ unsigned long long f4h4(float4 v) {
  union { unsigned long long q; __half h[4]; } c;
  c.h[0] = __float2half(v.x); c.h[1] = __float2half(v.y);
  c.h[2] = __float2half(v.z); c.h[3] = __float2half(v.w);
  return c.q;
}

// Fence-free hierarchical grid barrier (semantics proven in R7; tree cuts
// 256 serialized line-RMWs to 16/line). waitcnt(0) drains sc1 stores before
// arrival; readers use sc1 loads, so no cache maintenance is needed.
__device__ __forceinline__ void fastbar(unsigned* bar, unsigned& ep) {
  ++ep;
  __atomic_signal_fence(__ATOMIC_SEQ_CST);
  __builtin_amdgcn_s_waitcnt(0);
  __atomic_signal_fence(__ATOMIC_SEQ_CST);
  __syncthreads();
  if (threadIdx.x == 0) {
    unsigned* leaf = bar + (blockIdx.x & 15u) * 32u;
    unsigned a = atomicAdd(leaf, 1u);
    if (a == ep * 16u - 1u) {
      unsigned r = atomicAdd(bar + 512, 1u);
      if (r == ep * 16u - 1u)
        __hip_atomic_store(bar + 544, ep, __ATOMIC_RELAXED, __HIP_MEMORY_SCOPE_AGENT);
    }
    while (__hip_atomic_load(bar + 544, __ATOMIC_RELAXED, __HIP_MEMORY_SCOPE_AGENT) < ep)
      __builtin_amdgcn_s_sleep(1);
  }
  __syncthreads();
}

// ---- prologue helpers (256 blocks x 512 threads) --------------------------
__device__ __forceinline__ void stv(float* p, float v) { *p = v; }
__device__ __forceinline__ void stv(__half* p, float v) { *p = __float2half(v); }

template <int J, int N, int CPT, typename OT>
__device__ void matmat(const float* __restrict__ A, const float* __restrict__ B,
                       OT* __restrict__ C) {
  const int tid = threadIdx.x;
  const int r = blockIdx.x * 4 + (tid >> 7);
  const int c0 = tid & 127;
  float acc[CPT];
#pragma unroll
  for (int i = 0; i < CPT; ++i) acc[i] = 0.f;
  const float* ar = A + (size_t)r * J;
#pragma unroll 2
  for (int j = 0; j < J; ++j) {
    float av = ar[j];
    const float* br = B + (size_t)j * N + c0;
#pragma unroll
    for (int i = 0; i < CPT; ++i) acc[i] = fmaf(av, br[i * 128], acc[i]);
  }
  OT* cr = C + (size_t)r * N + c0;
#pragma unroll
  for (int i = 0; i < CPT; ++i) stv(cr + (size_t)i * 128, acc[i]);
}

// fp32 -> fp16 copy, float4 granularity. n4 = element_count/4.
__device__ void cvt_copy(const float* __restrict__ s, __half* __restrict__ d,
                         int n4) {
  for (int i = (int)(blockIdx.x * 512u + threadIdx.x); i < n4; i += 131072)
    *(unsigned long long*)(d + (size_t)i * 4) = f4h4(*(const float4*)(s + (size_t)i * 4));
}

__device__ void vecmat(const float* __restrict__ v, const float* __restrict__ M,
                       const float* __restrict__ badd, float* __restrict__ outv,
                       int J, int N, int blk0, int nblk) {
  int b = (int)blockIdx.x;
  if (b < blk0 || b >= blk0 + nblk) return;
  int gid = (b - blk0) * 512 + threadIdx.x;
  if (gid >= N) return;
  float acc = 0.f;
#pragma unroll 4
  for (int j = 0; j < J; ++j) acc = fmaf(v[j], M[(size_t)j * N + gid], acc);
  outv[gid] = acc + badd[gid];
}

__device__ void gemv1024(const float* __restrict__ A, const float* __restrict__ W,
                         const float* __restrict__ bias, int K, int relu,
                         float* __restrict__ C, float* __restrict__ C2,
                         float* __restrict__ C3, float* red) {
  const int tid = threadIdx.x;
  const int m = tid & 63, w = tid >> 6;
  const int j = w & 3, hh = w >> 2;
  const int c = blockIdx.x * 4 + j;
  const int kh = K >> 1;
  const float* a = A + m + (hh * kh) * 64;
  const float* wp = W + c + (size_t)(hh * kh) * 1024;
  float acc = 0.f;
#pragma unroll 8
  for (int k = 0; k < kh; ++k) acc = fmaf(a[k * 64], wp[(size_t)k * 1024], acc);
  if (hh) red[j * 64 + m] = acc;
  __syncthreads();
  if (!hh) {
    float v = acc + red[j * 64 + m] + bias[c];
    if (relu) v = fmaxf(v, 0.f);
    C[c * 64 + m] = v;
    if (C2) C2[c * 64 + m] = v;
    if (C3) C3[c * 64 + m] = v;
  }
  __syncthreads();
}

// ---- GRU matmul: 256 blocks = 32 col-groups(96) x 8 K-slices(256) ---------
// Weights fp16 (3x 8B loads/thread/chunk, cvt to fp32 at LDS write).
// Inner loop identical to R8 (fp32 LDS operands).
__device__ __forceinline__ void gru_mm(const __half* __restrict__ Wx,
                                       const float* __restrict__ actx,
                                       const __half* __restrict__ Whm,
                                       const float* __restrict__ acth,
                                       float* __restrict__ part,
                                       float* __restrict__ sm) {
  float* sa = sm;            // [2][64*64]
  float* sw = sm + 8192;     // [2][64*96]
  const int tid = threadIdx.x;
  const int bid = blockIdx.x;
  const int g = bid >> 3, s = bid & 7;
  const int c0 = g * 96;
  const int k0 = (s & 3) * 256;
  const __half* W = (s < 4 ? Wx : Whm);
  const float* A = (s < 4 ? actx : acth) + (size_t)k0 * 64;
  const int kr = tid >> 3, cs = (tid & 7) * 12;
  const int w = tid >> 6, lane = tid & 63;
  const int m = (w >> 2) * 32 + (lane & 31);
  const int cb = (w & 3) * 24 + (lane >> 5) * 12;

  float acc[12];
#pragma unroll
  for (int j = 0; j < 12; ++j) acc[j] = 0.f;
  unsigned long long av[4];
  unsigned long long wl[3];
  {  // stage chunk 0
    const unsigned long long* Ab = (const unsigned long long*)A;
#pragma unroll
    for (int i = 0; i < 4; ++i) av[i] = ald64(Ab + tid + i * 512);
    const __half* Wr = W + (size_t)(k0 + kr) * 3072 + c0 + cs;
    wl[0] = *(const unsigned long long*)Wr;
    wl[1] = *(const unsigned long long*)(Wr + 4);
    wl[2] = *(const unsigned long long*)(Wr + 8);
#pragma unroll
    for (int i = 0; i < 4; ++i) {
      int jj = tid + i * 512;
      *(unsigned long long*)(sa + ((jj >> 5) << 6) + ((jj & 31) << 1)) = av[i];
    }
    float* swr = sw + kr * 96 + cs;
    *(float4*)swr = h4f(wl[0]); *(float4*)(swr + 4) = h4f(wl[1]);
    *(float4*)(swr + 8) = h4f(wl[2]);
  }
  for (int ch = 0; ch < 4; ++ch) {
    const int buf = ch & 1;
    __syncthreads();
    if (ch < 3) {
      const unsigned long long* Ab = (const unsigned long long*)(A + (ch + 1) * 4096);
#pragma unroll
      for (int i = 0; i < 4; ++i) av[i] = ald64(Ab + tid + i * 512);
      const __half* Wr = W + (size_t)(k0 + (ch + 1) * 64 + kr) * 3072 + c0 + cs;
      wl[0] = *(const unsigned long long*)Wr;
      wl[1] = *(const unsigned long long*)(Wr + 4);
      wl[2] = *(const unsigned long long*)(Wr + 8);
    }
    const float* ap = sa + buf * 4096 + m;
    const float* wp = sw + buf * 6144 + cb;
#pragma unroll 8
    for (int k = 0; k < 64; ++k) {
      float a = ap[k * 64];
      float4 w0 = *(const float4*)(wp + k * 96);
      float4 w1 = *(const float4*)(wp + k * 96 + 4);
      float4 w2v = *(const float4*)(wp + k * 96 + 8);
      acc[0] = fmaf(a, w0.x, acc[0]);  acc[1] = fmaf(a, w0.y, acc[1]);
      acc[2] = fmaf(a, w0.z, acc[2]);  acc[3] = fmaf(a, w0.w, acc[3]);
      acc[4] = fmaf(a, w1.x, acc[4]);  acc[5] = fmaf(a, w1.y, acc[5]);
      acc[6] = fmaf(a, w1.z, acc[6]);  acc[7] = fmaf(a, w1.w, acc[7]);
      acc[8] = fmaf(a, w2v.x, acc[8]); acc[9] = fmaf(a, w2v.y, acc[9]);
      acc[10] = fmaf(a, w2v.z, acc[10]); acc[11] = fmaf(a, w2v.w, acc[11]);
    }
    if (ch < 3) {
      const int nb = buf ^ 1;
#pragma unroll
      for (int i = 0; i < 4; ++i) {
        int jj = tid + i * 512;
        *(unsigned long long*)(sa + nb * 4096 + ((jj >> 5) << 6) + ((jj & 31) << 1)) = av[i];
      }
      float* swr = sw + nb * 6144 + kr * 96 + cs;
      *(float4*)swr = h4f(wl[0]); *(float4*)(swr + 4) = h4f(wl[1]);
      *(float4*)(swr + 8) = h4f(wl[2]);
    }
  }
  float* pb = part + ((size_t)s * 3072 + c0 + cb) * 64 + m;
#pragma unroll
  for (int j = 0; j < 12; ++j) ast(pb + (size_t)j * 64, acc[j]);
}

// GRU combine: 8 K-slices (0-3 x-part, 4-7 h-part). 256 blocks, 256 thr.
__device__ __forceinline__ void gru_comb(const float* __restrict__ part,
                                         const float* __restrict__ bx,
                                         const float* __restrict__ bm,
                                         float* __restrict__ h) {
  const int tid = threadIdx.x, bid = blockIdx.x;
  if (tid >= 256) return;
  const int c = bid * 4 + (tid >> 6), m = tid & 63;
  float ra = 0.f, za = 0.f, ia = 0.f, na = 0.f;
#pragma unroll
  for (int s = 0; s < 8; ++s) {
    const float* ps = part + (size_t)s * 3072 * 64;
    ra += ald(ps + (size_t)c * 64 + m);
    za += ald(ps + (size_t)(1024 + c) * 64 + m);
    float nv = ald(ps + (size_t)(2048 + c) * 64 + m);
    if (s < 4) ia += nv; else na += nv;
  }
  float r  = 1.f / (1.f + expf(-(ra + bx[c] + bm[c])));
  float zg = 1.f / (1.f + expf(-(za + bx[1024 + c] + bm[1024 + c])));
  float nn = tanhf(ia + bx[2048 + c] + r * (na + bm[2048 + c]));
  float hp = ald(h + (size_t)c * 64 + m);
  ast(h + (size_t)c * 64 + m, (1.f - zg) * nn + zg * hp);
}

// P5: C=1280 (1024 WhW1 | 256 Wh), 32 groups(40) x 8 K-slices(128).
// Weights fp16: 5 scalar half loads/thread/chunk, cvt at load.
__device__ __forceinline__ void p5_mm(const __half* __restrict__ WhW1,
                                      const __half* __restrict__ Whd,
                                      const float* __restrict__ h2,
                                      float* __restrict__ part,
                                      float* __restrict__ sm) {
  float* sa = sm;            // [2][4096]
  float* sw = sm + 8192;     // [2][4096] rows of 64 (8 waves x 8 slots)
  const int tid = threadIdx.x;
  const int bid = blockIdx.x;
  const int g = bid >> 3, s = bid & 7;
  const int c0 = g * 40;
  const int k0 = s * 128;
  const float* A = h2 + (size_t)k0 * 64;
  const int kr = tid >> 3, ci = (tid & 7) * 5;
  const int w = tid >> 6, lane = tid & 63;
  float acc[5] = {0.f, 0.f, 0.f, 0.f, 0.f};
  unsigned long long av[4];
  float wl[5];
#define P5LD(chk, jj) \
  ({ int gc = c0 + ci + (jj); int krow = k0 + (chk) * 64 + kr; \
     __half2float((gc < 1024) ? WhW1[(size_t)krow * 1024 + gc] \
                              : Whd[(size_t)krow * 256 + (gc - 1024)]); })
  {
    const unsigned long long* Ab = (const unsigned long long*)A;
#pragma unroll
    for (int i = 0; i < 4; ++i) av[i] = ald64(Ab + tid + i * 512);
#pragma unroll
    for (int jj = 0; jj < 5; ++jj) wl[jj] = P5LD(0, jj);
#pragma unroll
    for (int i = 0; i < 4; ++i) {
      int jj = tid + i * 512;
      *(unsigned long long*)(sa + ((jj >> 5) << 6) + ((jj & 31) << 1)) = av[i];
    }
#pragma unroll
    for (int jj = 0; jj < 5; ++jj) sw[kr * 64 + (tid & 7) * 8 + jj] = wl[jj];
  }
  for (int ch = 0; ch < 2; ++ch) {
    const int buf = ch & 1;
    __syncthreads();
    if (ch < 1) {
      const unsigned long long* Ab = (const unsigned long long*)(A + 4096);
#pragma unroll
      for (int i = 0; i < 4; ++i) av[i] = ald64(Ab + tid + i * 512);
#pragma unroll
      for (int jj = 0; jj < 5; ++jj) wl[jj] = P5LD(1, jj);
    }
    const float* ap = sa + buf * 4096 + lane;
    const float* wp = sw + buf * 4096 + w * 8;
#pragma unroll 8
    for (int k = 0; k < 64; ++k) {
      float a = ap[k * 64];
      float4 w4 = *(const float4*)(wp + k * 64);
      float w1v = wp[k * 64 + 4];
      acc[0] = fmaf(a, w4.x, acc[0]); acc[1] = fmaf(a, w4.y, acc[1]);
      acc[2] = fmaf(a, w4.z, acc[2]); acc[3] = fmaf(a, w4.w, acc[3]);
      acc[4] = fmaf(a, w1v, acc[4]);
    }
    if (ch < 1) {
#pragma unroll
      for (int i = 0; i < 4; ++i) {
        int jj = tid + i * 512;
        *(unsigned long long*)(sa + 4096 + ((jj >> 5) << 6) + ((jj & 31) << 1)) = av[i];
      }
#pragma unroll
      for (int jj = 0; jj < 5; ++jj) sw[4096 + kr * 64 + (tid & 7) * 8 + jj] = wl[jj];
    }
  }
#undef P5LD
  float* pb = part + ((size_t)s * 1280 + c0 + w * 5) * 64 + lane;
#pragma unroll
  for (int j = 0; j < 5; ++j) ast(pb + (size_t)j * 64, acc[j]);
}

// P5 combine: t1 cols 0..1023 (tid<256), out cols 1024..1279 (tid 256..319).
__device__ __forceinline__ void p5b(const float* __restrict__ part,
                                    const float* __restrict__ bhw1,
                                    const float* __restrict__ bh,
                                    float* __restrict__ t1, float* __restrict__ out,
                                    int t) {
  const int tid = threadIdx.x, bid = blockIdx.x;
  if (tid < 256) {
    const int c = bid * 4 + (tid >> 6), m = tid & 63;
    float v = 0.f;
#pragma unroll
    for (int s = 0; s < 8; ++s) v += ald(part + ((size_t)s * 1280 + c) * 64 + m);
    ast(t1 + (size_t)c * 64 + m, fmaxf(v + bhw1[c], 0.f));
  } else if (tid < 320) {
    const int m = tid - 256, c2 = bid;
    float v = 0.f;
#pragma unroll
    for (int s = 0; s < 8; ++s) v += ald(part + ((size_t)s * 1280 + 1024 + c2) * 64 + m);
    out[(size_t)(m * TSTEP + t) * LATD + c2] = v + bh[c2];
  }
}

// P6: C=1024, 32 groups(32) x 8 K-slices(128). Weights fp16: one 8B load.
__device__ __forceinline__ void p6_mm(const __half* __restrict__ w2h,
                                      const float* __restrict__ t1,
                                      float* __restrict__ part,
                                      float* __restrict__ sm) {
  float* sa = sm;            // [2][4096]
  float* sw = sm + 8192;     // [2][2048] rows of 32
  const int tid = threadIdx.x;
  const int bid = blockIdx.x;
  const int g = bid >> 3, s = bid & 7;
  const int c0 = g * 32;
  const int k0 = s * 128;
  const float* A = t1 + (size_t)k0 * 64;
  const int kr = tid >> 3, ci = (tid & 7) * 4;
  const int w = tid >> 6, lane = tid & 63;
  float acc[4] = {0.f, 0.f, 0.f, 0.f};
  unsigned long long av[4];
  unsigned long long wl;
  {
    const unsigned long long* Ab = (const unsigned long long*)A;
#pragma unroll
    for (int i = 0; i < 4; ++i) av[i] = ald64(Ab + tid + i * 512);
    wl = *(const unsigned long long*)(w2h + (size_t)(k0 + kr) * 1024 + c0 + ci);
#pragma unroll
    for (int i = 0; i < 4; ++i) {
      int jj = tid + i * 512;
      *(unsigned long long*)(sa + ((jj >> 5) << 6) + ((jj & 31) << 1)) = av[i];
    }
    *(float4*)(sw + kr * 32 + ci) = h4f(wl);
  }
  for (int ch = 0; ch < 2; ++ch) {
    const int buf = ch & 1;
    __syncthreads();
    if (ch < 1) {
      const unsigned long long* Ab = (const unsigned long long*)(A + 4096);
#pragma unroll
      for (int i = 0; i < 4; ++i) av[i] = ald64(Ab + tid + i * 512);
      wl = *(const unsigned long long*)(w2h + (size_t)(k0 + 64 + kr) * 1024 + c0 + ci);
    }
    const float* ap = sa + buf * 4096 + lane;
    const float* wp = sw + buf * 2048 + w * 4;
#pragma unroll 8
    for (int k = 0; k < 64; ++k) {
      float a = ap[k * 64];
      float4 w4 = *(const float4*)(wp + k * 32);
      acc[0] = fmaf(a, w4.x, acc[0]); acc[1] = fmaf(a, w4.y, acc[1]);
      acc[2] = fmaf(a, w4.z, acc[2]); acc[3] = fmaf(a, w4.w, acc[3]);
    }
    if (ch < 1) {
#pragma unroll
      for (int i = 0; i < 4; ++i) {
        int jj = tid + i * 512;
        *(unsigned long long*)(sa + 4096 + ((jj >> 5) << 6) + ((jj & 31) << 1)) = av[i];
      }
      *(float4*)(sw + 2048 + kr * 32 + ci) = h4f(wl);
    }
  }
  float* pb = part + ((size_t)s * 1024 + c0 + w * 4) * 64 + lane;
#pragma unroll
  for (int j = 0; j < 4; ++j) ast(pb + (size_t)j * 64, acc[j]);
}

__device__ __forceinline__ void p6b(const float* __restrict__ part,
                                    const float* __restrict__ b2,
                                    float* __restrict__ gin) {
  const int tid = threadIdx.x, bid = blockIdx.x;
  if (tid >= 256) return;
  const int c = bid * 4 + (tid >> 6), m = tid & 63;
  float v = 0.f;
#pragma unroll
  for (int s = 0; s < 8; ++s) v += ald(part + ((size_t)s * 1024 + c) * 64 + m);
  ast(gin + (size_t)c * 64 + m, fmaxf(v + b2[c], 0.f));
}

__global__ __launch_bounds__(512, 1) void persist(P p) {
  cg::grid_group grid = cg::this_grid();
  __shared__ float sm[20480];   // 80 KB: [acts 2x4096 | weights 2x6144]
  unsigned ep = 0;

  // ---- prologue (4 slow cg syncs; their fences flush prologue's normal
  //      stores so loop-side cached weight reads + sc1 act reads start clean)
  if (blockIdx.x == 0) {
    for (int i = threadIdx.x; i < 1024; i += 512) p.bar[i] = 0u;
  }
  if (threadIdx.x < 64) {  // z transpose -> h1 region (consumed pre-overwrite)
    int i = blockIdx.x * 64 + threadIdx.x;
    int m = i >> 8, l = i & 255;
    p.h1[l * 64 + m] = p.z[i];
  }
  matmat<1024, 1024, 8>(p.Wv, p.Wo, p.part);            // Wvo (fp32 temp)
  vecmat(p.bh, p.w1, p.b1, p.bhw1, 256, 1024, 0, 2);
  vecmat(p.bv, p.Wo, p.bo, p.bvo, 1024, 1024, 2, 2);
  cvt_copy(p.Whh0, p.Whh0h, 786432);                    // raw weights -> fp16
  cvt_copy(p.Wih1, p.Wih1h, 786432);
  cvt_copy(p.Whh1, p.Whh1h, 786432);
  cvt_copy(p.w2,   p.w2h,   262144);
  cvt_copy(p.Wh,   p.Whh,   65536);
  grid.sync();
  matmat<1024, 3072, 24>(p.part, p.Wih0, p.Wvoihh);     // Wvoih -> fp16 direct
  matmat<256, 1024, 8>(p.Wh, p.w1, p.WhW1h);            // WhW1 -> fp16 direct
  vecmat(p.bvo, p.Wih0, p.bih0, p.bfold, 1024, 3072, 0, 6);
  grid.sync();
  gemv1024(p.h1, p.w1, p.b1, 256, 1, p.t1, nullptr, nullptr, sm);
  grid.sync();
  gemv1024(p.t1, p.w2, p.b2, 1024, 0, p.h1, p.h2, p.gin, sm);
  grid.sync();

  // ---- time loop: 8 fence-free phases/step ----
  for (int t = 0; t < TSTEP; ++t) {
    gru_mm(p.Wvoihh, p.gin, p.Whh0h, p.h1, p.part, sm); fastbar(p.bar, ep);
    gru_comb(p.part, p.bfold, p.bhh0, p.h1);            fastbar(p.bar, ep);
    gru_mm(p.Wih1h, p.h1, p.Whh1h, p.h2, p.part, sm);   fastbar(p.bar, ep);
    gru_comb(p.part, p.bih1, p.bhh1, p.h2);             fastbar(p.bar, ep);
    p5_mm(p.WhW1h, p.Whh, p.h2, p.part, sm);            fastbar(p.bar, ep);
    p5b(p.part, p.bhw1, p.bh, p.t1, p.out, t);          fastbar(p.bar, ep);
    p6_mm(p.w2h, p.t1, p.part, sm);                     fastbar(p.bar, ep);
    p6b(p.part, p.b2, p.gin);                           fastbar(p.bar, ep);
  }
}

// ---------------------------------------------------------------------------
// Fallback path (round-2 verified multi-kernel, fp32 — unchanged).
// ---------------------------------------------------------------------------
__global__ void fb_transpose(const float* __restrict__ z, float* __restrict__ zT) {
  int i = blockIdx.x * 256 + threadIdx.x;
  int m = i >> 8, l = i & 255;
  zT[l * 64 + m] = z[i];
}
__global__ void fb_copy2(const float* __restrict__ s, float* __restrict__ d1,
                         float* __restrict__ d2) {
  int i = blockIdx.x * 256 + threadIdx.x;
  float v = s[i]; d1[i] = v; d2[i] = v;
}
template <int ACT>
__global__ void fb_gemm(const float* __restrict__ A_T, const float* __restrict__ W,
                        const float* __restrict__ bias, float* __restrict__ C_T,
                        int K, int N, float* __restrict__ outp, int tstep) {
  const int m = threadIdx.x & 63;
  const int wv = threadIdx.x >> 6;
  const int c = blockIdx.x * 4 + wv;
  float acc0 = 0.f, acc1 = 0.f;
  const float* ap = A_T + m;
  const float* wp = W + c;
#pragma unroll 4
  for (int k = 0; k + 1 < K; k += 2) {
    acc0 = fmaf(ap[k * 64], wp[(size_t)k * N], acc0);
    acc1 = fmaf(ap[(k + 1) * 64], wp[(size_t)(k + 1) * N], acc1);
  }
  float v0 = acc0 + acc1 + bias[c];
  if (ACT) v0 = fmaxf(v0, 0.f);
  C_T[c * 64 + m] = v0;
  if (outp != nullptr) outp[(size_t)(m * TSTEP + tstep) * LATD + c] = v0;
}
__global__ void fb_gru(const float* __restrict__ xT, const float* __restrict__ hT,
                       const float* __restrict__ Wih, const float* __restrict__ Whh,
                       const float* __restrict__ bih, const float* __restrict__ bhh,
                       float* __restrict__ hnT) {
  const int m = threadIdx.x & 63;
  const int wv = threadIdx.x >> 6;
  const int c = blockIdx.x * 4 + wv;
  float racc = 0, zacc = 0, iacc = 0, nacc = 0;
  const float* xp = xT + m;
  const float* hp = hT + m;
  const float* wi = Wih + c;
  const float* wh = Whh + c;
#pragma unroll 2
  for (int k = 0; k < 1024; ++k) {
    float a = xp[k * 64];
    float h = hp[k * 64];
    const float* wik = wi + (size_t)k * 3072;
    const float* whk = wh + (size_t)k * 3072;
    racc = fmaf(a, wik[0], racc); racc = fmaf(h, whk[0], racc);
    zacc = fmaf(a, wik[1024], zacc); zacc = fmaf(h, whk[1024], zacc);
    iacc = fmaf(a, wik[2048], iacc);
    nacc = fmaf(h, whk[2048], nacc);
  }
  float r = 1.f / (1.f + expf(-(racc + bih[c] + bhh[c])));
  float zg = 1.f / (1.f + expf(-(zacc + bih[1024 + c] + bhh[1024 + c])));
  float nn = tanhf(iacc + bih[2048 + c] + r * (nacc + bhh[2048 + c]));
  hnT[c * 64 + m] = (1.f - zg) * nn + zg * hT[c * 64 + m];
}

extern "C" void kernel_launch(void* const* d_in, const int* in_sizes, int n_in,
                              void* d_out, int out_size, void* d_ws, size_t ws_size,
                              hipStream_t stream) {
  const float* z_start = (const float*)d_in[0];
  const float* w1 = (const float*)d_in[2];
  const float* b1 = (const float*)d_in[3];
  const float* w2 = (const float*)d_in[4];
  const float* b2 = (const float*)d_in[5];
  const float* Wv = (const float*)d_in[10];
  const float* bv = (const float*)d_in[11];
  const float* Wo = (const float*)d_in[12];
  const float* bo = (const float*)d_in[13];
  const float* Wih0 = (const float*)d_in[14];
  const float* Whh0 = (const float*)d_in[15];
  const float* bih0 = (const float*)d_in[16];
  const float* bhh0 = (const float*)d_in[17];
  const float* Wih1 = (const float*)d_in[18];
  const float* Whh1 = (const float*)d_in[19];
  const float* bih1 = (const float*)d_in[20];
  const float* bhh1 = (const float*)d_in[21];
  const float* Wh = (const float*)d_in[22];
  const float* bh = (const float*)d_in[23];
  float* out = (float*)d_out;
  float* ws = (float*)d_ws;

  // floats: 4x1572864 (Wvoih_h,Whh0_h,Wih1_h,Whh1_h) + part 1572864 +
  // 524288x2 (WhW1_h,w2_h) + 131072 (Wh_h) + 4x65536 acts + 5120 small + 1024
  const size_t need = (size_t)9312256 * 4;
  if (ws_size >= need) {
    P p;
    p.z = z_start; p.w1 = w1; p.b1 = b1; p.w2 = w2; p.b2 = b2;
    p.Wv = Wv; p.bv = bv; p.Wo = Wo; p.bo = bo;
    p.Wih0 = Wih0; p.Whh0 = Whh0; p.bih0 = bih0; p.bhh0 = bhh0;
    p.Wih1 = Wih1; p.Whh1 = Whh1; p.bih1 = bih1; p.bhh1 = bhh1;
    p.Wh = Wh; p.bh = bh; p.out = out;
    float* q = ws;
    p.Wvoihh = (__half*)q; q += 1572864;   // 1024x3072 halves
    p.Whh0h  = (__half*)q; q += 1572864;
    p.Wih1h  = (__half*)q; q += 1572864;
    p.Whh1h  = (__half*)q; q += 1572864;
    p.WhW1h  = (__half*)q; q += 524288;    // 1024x1024 halves
    p.Whh    = (__half*)q; q += 131072;    // 1024x256 halves
    p.w2h    = (__half*)q; q += 524288;
    p.part = q; q += 1572864;   // Wvo fp32 temp in prologue; partials in loop
    p.gin = q; q += 65536;
    p.h1 = q; q += 65536;       // also zT during prologue
    p.h2 = q; q += 65536;
    p.t1 = q; q += 65536;
    p.bvo = q; q += 1024;
    p.bfold = q; q += 3072;
    p.bhw1 = q; q += 1024;
    p.bar = (unsigned*)q; q += 1024;
    void* args[] = { &p };
    hipError_t e = hipLaunchCooperativeKernel((const void*)persist, dim3(256),
                                              dim3(512), args, 0, stream);
    if (e == hipSuccess) return;
  }

  // -------- fallback: verified round-2 path --------
  float* zsT = ws;
  float* vT = zsT + 16384;
  float* xaT = vT + 65536;
  float* t1T = xaT + 65536;
  float* ginT = t1T + 65536;
  float* nzT = ginT + 65536;
  float* h1T = nzT + 16384;
  float* h2T = h1T + 2 * 65536;

  fb_transpose<<<64, 256, 0, stream>>>(z_start, zsT);
  fb_gemm<1><<<256, 256, 0, stream>>>(zsT, w1, b1, t1T, 256, 1024, nullptr, 0);
  fb_gemm<0><<<256, 256, 0, stream>>>(t1T, w2, b2, h1T, 1024, 1024, nullptr, 0);
  fb_copy2<<<256, 256, 0, stream>>>(h1T, h2T, ginT);
  for (int t = 0; t < TSTEP; ++t) {
    float* h1p = h1T + (t & 1) * 65536;
    float* h1n = h1T + ((t + 1) & 1) * 65536;
    float* h2p = h2T + (t & 1) * 65536;
    float* h2n = h2T + ((t + 1) & 1) * 65536;
    fb_gemm<0><<<256, 256, 0, stream>>>(ginT, Wv, bv, vT, 1024, 1024, nullptr, 0);
    fb_gemm<0><<<256, 256, 0, stream>>>(vT, Wo, bo, xaT, 1024, 1024, nullptr, 0);
    fb_gru<<<256, 256, 0, stream>>>(xaT, h1p, Wih0, Whh0, bih0, bhh0, h1n);
    fb_gru<<<256, 256, 0, stream>>>(h1n, h2p, Wih1, Whh1, bih1, bhh1, h2n);
    fb_gemm<0><<<64, 256, 0, stream>>>(h2n, Wh, bh, nzT, 1024, 256, out, t);
    fb_gemm<1><<<256, 256, 0, stream>>>(nzT, w1, b1, t1T, 256, 1024, nullptr, 0);
    fb_gemm<1><<<256, 256, 0, stream>>>(t1T, w2, b2, ginT, 1024, 1024, nullptr, 0);
  }
}

// Round 4
// 13371.312 us; speedup vs baseline: 1.0980x; 1.0289x over previous
//
#include <hip/hip_runtime.h>
#include <hip/hip_cooperative_groups.h>
#include <hip/hip_fp16.h>

namespace cg = cooperative_groups;

#define TSTEP 128
#define LATD 256

// ---------------------------------------------------------------------------
// R11 = R10 with the LDS overflow fixed. R10 failed absmax 4.2e-2: planeB is
// [256][32] HALVES = 4096 floats, but sm was sized for 2048 -> staging wrote
// 8 KB past the allocation for k in [128,256), corrupting cols 8-11 of every
// 12-col group for ksub>=2. Fix: sm[28672] (112 KB; 160 KB/CU pool, still
// 1 block/CU). No other changes -- isolates the R10 register-blocking theory:
// gru_mm was LDS-ISSUE-bound (4 LDS instr per 12 FMA, 8 waves on one LDS
// pipe ~22 us vs 5 us FMA). Now: 4-way K-subset split (128 thr each own one
// 64-k chunk), per-thread 4m x 12c tile (48 acc): 3 LDS instr (act b128 +
// w b128 + w b64 fp16) per 48 FMA = 16 FMA/instr. LDS tree-reduce across
// ksubs, ksub0 writes part. p6 same treatment (4x4 tile). p5, combines,
// part layout, fastbar, prologue, phases: UNCHANGED from R9 (verified).
// Folds (verified R3-R9): Wvoih=(Wv@Wo)@Wih0, bfold=(bv@Wo+bo)@Wih0+bih0,
// WhW1=Wh@w1, bhw1=bh@w1+b1. Step = 8 phases.
// ---------------------------------------------------------------------------

typedef __attribute__((ext_vector_type(2))) unsigned long long u64x2;

struct P {
  const float *z, *w1, *b1, *w2, *b2, *Wv, *bv, *Wo, *bo;
  const float *Wih0, *Whh0, *bih0, *bhh0, *Wih1, *Whh1, *bih1, *bhh1, *Wh, *bh;
  float *out;
  __half *Wvoihh, *Whh0h, *Wih1h, *Whh1h, *WhW1h, *Whh, *w2h;
  float *part, *gin, *h1, *h2, *t1, *bvo, *bfold, *bhw1;
  unsigned *bar;   // leaves at i*32 (i<16), root at 512, flag at 544
};

__device__ __forceinline__ float ald(const float* p) {
  return __hip_atomic_load((float*)p, __ATOMIC_RELAXED, __HIP_MEMORY_SCOPE_AGENT);
}
__device__ __forceinline__ void ast(float* p, float v) {
  __hip_atomic_store(p, v, __ATOMIC_RELAXED, __HIP_MEMORY_SCOPE_AGENT);
}
__device__ __forceinline__ unsigned long long ald64(const unsigned long long* p) {
  return __hip_atomic_load((unsigned long long*)p, __ATOMIC_RELAXED,
                           __HIP_MEMORY_SCOPE_AGENT);
}

// 4 packed halves -> float4 (staging helpers).
__device__ __forceinline__ float4 h4f(unsigned long long u) {
  union { unsigned long long q; __half h[4]; } c; c.q = u;
  return make_float4(__half2float(c.h[0]), __half2float(c.h[1]),
                     __half2float(c.h[2]), __half2float(c.h[3]));
}
__device__ __forceinline__ unsigned long long f4h4(float4 v) {
  union { unsigned long long q; __half h[4]; } c;
  c.h[0] = __float2half(v.x); c.h[1] = __float2half(v.y);
  c.h[2] = __float2half(v.z); c.h[3] = __float2half(v.w);
  return c.q;
}

// Fence-free hierarchical grid barrier (semantics proven in R7).
__device__ __forceinline__ void fastbar(unsigned* bar, unsigned& ep) {
  ++ep;
  __atomic_signal_fence(__ATOMIC_SEQ_CST);
  __builtin_amdgcn_s_waitcnt(0);
  __atomic_signal_fence(__ATOMIC_SEQ_CST);
  __syncthreads();
  if (threadIdx.x == 0) {
    unsigned* leaf = bar + (blockIdx.x & 15u) * 32u;
    unsigned a = atomicAdd(leaf, 1u);
    if (a == ep * 16u - 1u) {
      unsigned r = atomicAdd(bar + 512, 1u);
      if (r == ep * 16u - 1u)
        __hip_atomic_store(bar + 544, ep, __ATOMIC_RELAXED, __HIP_MEMORY_SCOPE_AGENT);
    }
    while (__hip_atomic_load(bar + 544, __ATOMIC_RELAXED, __HIP_MEMORY_SCOPE_AGENT) < ep)
      __builtin_amdgcn_s_sleep(1);
  }
  __syncthreads();
}

// ---- prologue helpers (256 blocks x 512 threads) --------------------------
__device__ __forceinline__ void stv(float* p, float v) { *p = v; }
__device__ __forceinline__ void stv(__half* p, float v) { *p = __float2half(v); }

template <int J, int N, int CPT, typename OT>
__device__ void matmat(const float* __restrict__ A, const float* __restrict__ B,
                       OT* __restrict__ C) {
  const int tid = threadIdx.x;
  const int r = blockIdx.x * 4 + (tid >> 7);
  const int c0 = tid & 127;
  float acc[CPT];
#pragma unroll
  for (int i = 0; i < CPT; ++i) acc[i] = 0.f;
  const float* ar = A + (size_t)r * J;
#pragma unroll 2
  for (int j = 0; j < J; ++j) {
    float av = ar[j];
    const float* br = B + (size_t)j * N + c0;
#pragma unroll
    for (int i = 0; i < CPT; ++i) acc[i] = fmaf(av, br[i * 128], acc[i]);
  }
  OT* cr = C + (size_t)r * N + c0;
#pragma unroll
  for (int i = 0; i < CPT; ++i) stv(cr + (size_t)i * 128, acc[i]);
}

// fp32 -> fp16 copy, float4 granularity. n4 = element_count/4.
__device__ void cvt_copy(const float* __restrict__ s, __half* __restrict__ d,
                         int n4) {
  for (int i = (int)(blockIdx.x * 512u + threadIdx.x); i < n4; i += 131072)
    *(unsigned long long*)(d + (size_t)i * 4) = f4h4(*(const float4*)(s + (size_t)i * 4));
}

__device__ void vecmat(const float* __restrict__ v, const float* __restrict__ M,
                       const float* __restrict__ badd, float* __restrict__ outv,
                       int J, int N, int blk0, int nblk) {
  int b = (int)blockIdx.x;
  if (b < blk0 || b >= blk0 + nblk) return;
  int gid = (b - blk0) * 512 + threadIdx.x;
  if (gid >= N) return;
  float acc = 0.f;
#pragma unroll 4
  for (int j = 0; j < J; ++j) acc = fmaf(v[j], M[(size_t)j * N + gid], acc);
  outv[gid] = acc + badd[gid];
}

__device__ void gemv1024(const float* __restrict__ A, const float* __restrict__ W,
                         const float* __restrict__ bias, int K, int relu,
                         float* __restrict__ C, float* __restrict__ C2,
                         float* __restrict__ C3, float* red) {
  const int tid = threadIdx.x;
  const int m = tid & 63, w = tid >> 6;
  const int j = w & 3, hh = w >> 2;
  const int c = blockIdx.x * 4 + j;
  const int kh = K >> 1;
  const float* a = A + m + (hh * kh) * 64;
  const float* wp = W + c + (size_t)(hh * kh) * 1024;
  float acc = 0.f;
#pragma unroll 8
  for (int k = 0; k < kh; ++k) acc = fmaf(a[k * 64], wp[(size_t)k * 1024], acc);
  if (hh) red[j * 64 + m] = acc;
  __syncthreads();
  if (!hh) {
    float v = acc + red[j * 64 + m] + bias[c];
    if (relu) v = fmaxf(v, 0.f);
    C[c * 64 + m] = v;
    if (C2) C2[c * 64 + m] = v;
    if (C3) C3[c * 64 + m] = v;
  }
  __syncthreads();
}

// ---- GRU matmul: 256 blocks = 32 col-groups(96) x 8 K-slices(256) ---------
// 4 ksubs x 128 thr; ksub owns 64 k. Thread: 4m x 12c tile (48 acc).
// LDS: acts fp32 [256][64] at sm[0] (16384 f); planeA [256][64]h at
// sm+16384 (8192 f; first 8 halves of each 12-col group); planeB [256][32]h
// at sm+24576 (4096 f; last 4 halves). Total 28672 f = 112 KB.
// Per k: 1 b128 act + 1 b128 wA + 1 b64 wB = 3 LDS instr / 48 FMA.
__device__ __forceinline__ void gru_mm(const __half* __restrict__ Wx,
                                       const float* __restrict__ actx,
                                       const __half* __restrict__ Whm,
                                       const float* __restrict__ acth,
                                       float* __restrict__ part,
                                       float* __restrict__ sm) {
  const int tid = threadIdx.x;
  const int bid = blockIdx.x;
  const int g = bid >> 3, s = bid & 7;
  const int c0 = g * 96;
  const int k0 = (s & 3) * 256;
  const __half* W = (s < 4 ? Wx : Whm);
  const float* A = (s < 4 ? actx : acth) + (size_t)k0 * 64;

  // ---- stage acts (8192 dw) ----
  {
    const unsigned long long* Ab = (const unsigned long long*)A;
    unsigned long long* Sb = (unsigned long long*)sm;
#pragma unroll
    for (int i = 0; i < 16; ++i) Sb[tid + i * 512] = ald64(Ab + tid + i * 512);
  }
  // ---- stage weights fp16 -> planes (thread: k=tid>>1, 48 halves) ----
  {
    const int k = tid >> 1, hr = tid & 1;
    const unsigned long long* Wr =
        (const unsigned long long*)(W + (size_t)(k0 + k) * 3072 + c0) + hr * 12;
    unsigned long long* pa = (unsigned long long*)(sm + 16384) + k * 16 + hr * 8;
    unsigned long long* pb = (unsigned long long*)(sm + 24576) + k * 8 + hr * 4;
#pragma unroll
    for (int j = 0; j < 4; ++j) {
      unsigned long long q0 = Wr[j * 3];
      unsigned long long q1 = Wr[j * 3 + 1];
      unsigned long long q2 = Wr[j * 3 + 2];
      pa[j * 2] = q0; pa[j * 2 + 1] = q1; pb[j] = q2;
    }
  }
  __syncthreads();

  const int ksub = tid >> 7, u = tid & 127;
  const int mq = u & 15, cg = u >> 4;
  float acc[48];
#pragma unroll
  for (int j = 0; j < 48; ++j) acc[j] = 0.f;
  const float* ap = sm + (size_t)(ksub * 64) * 64 + mq * 4;
  const __half* wa = (const __half*)(sm + 16384) + (size_t)(ksub * 64) * 64 + cg * 8;
  const __half* wb = (const __half*)(sm + 24576) + (size_t)(ksub * 64) * 32 + cg * 4;
#pragma unroll 2
  for (int k = 0; k < 64; ++k) {
    float4 a4 = *(const float4*)(ap + k * 64);
    union { u64x2 v; __half h[8]; } ua;
    ua.v = *(const u64x2*)(wa + k * 64);
    union { unsigned long long v; __half h[4]; } ub;
    ub.v = *(const unsigned long long*)(wb + k * 32);
#pragma unroll
    for (int c = 0; c < 8; ++c) {
      float wf = __half2float(ua.h[c]);
      acc[c * 4 + 0] = fmaf(a4.x, wf, acc[c * 4 + 0]);
      acc[c * 4 + 1] = fmaf(a4.y, wf, acc[c * 4 + 1]);
      acc[c * 4 + 2] = fmaf(a4.z, wf, acc[c * 4 + 2]);
      acc[c * 4 + 3] = fmaf(a4.w, wf, acc[c * 4 + 3]);
    }
#pragma unroll
    for (int c = 0; c < 4; ++c) {
      float wf = __half2float(ub.h[c]);
      acc[32 + c * 4 + 0] = fmaf(a4.x, wf, acc[32 + c * 4 + 0]);
      acc[32 + c * 4 + 1] = fmaf(a4.y, wf, acc[32 + c * 4 + 1]);
      acc[32 + c * 4 + 2] = fmaf(a4.z, wf, acc[32 + c * 4 + 2]);
      acc[32 + c * 4 + 3] = fmaf(a4.w, wf, acc[32 + c * 4 + 3]);
    }
  }
  // ---- ksub tree-reduce in LDS (acts/weights dead; 18432 f < 28672) ----
  __syncthreads();
  float* red = sm;   // 3 * 6144 floats
  if (ksub) {
    float4* rp = (float4*)(red + (size_t)(ksub - 1) * 6144 + (size_t)u * 48);
#pragma unroll
    for (int j = 0; j < 12; ++j)
      rp[j] = make_float4(acc[4 * j], acc[4 * j + 1], acc[4 * j + 2], acc[4 * j + 3]);
  }
  __syncthreads();
  if (!ksub) {
#pragma unroll
    for (int q = 0; q < 3; ++q) {
      const float4* rp = (const float4*)(red + (size_t)q * 6144 + (size_t)u * 48);
#pragma unroll
      for (int j = 0; j < 12; ++j) {
        float4 r4 = rp[j];
        acc[4 * j] += r4.x; acc[4 * j + 1] += r4.y;
        acc[4 * j + 2] += r4.z; acc[4 * j + 3] += r4.w;
      }
    }
    float* pb0 = part + ((size_t)s * 3072 + c0 + cg * 12) * 64 + mq * 4;
#pragma unroll
    for (int c = 0; c < 8; ++c) {
      ast(pb0 + (size_t)c * 64 + 0, acc[c * 4 + 0]);
      ast(pb0 + (size_t)c * 64 + 1, acc[c * 4 + 1]);
      ast(pb0 + (size_t)c * 64 + 2, acc[c * 4 + 2]);
      ast(pb0 + (size_t)c * 64 + 3, acc[c * 4 + 3]);
    }
#pragma unroll
    for (int c = 0; c < 4; ++c) {
      ast(pb0 + (size_t)(8 + c) * 64 + 0, acc[32 + c * 4 + 0]);
      ast(pb0 + (size_t)(8 + c) * 64 + 1, acc[32 + c * 4 + 1]);
      ast(pb0 + (size_t)(8 + c) * 64 + 2, acc[32 + c * 4 + 2]);
      ast(pb0 + (size_t)(8 + c) * 64 + 3, acc[32 + c * 4 + 3]);
    }
  }
}

// GRU combine: 8 K-slices (0-3 x-part, 4-7 h-part). 256 blocks, 256 thr.
__device__ __forceinline__ void gru_comb(const float* __restrict__ part,
                                         const float* __restrict__ bx,
                                         const float* __restrict__ bm,
                                         float* __restrict__ h) {
  const int tid = threadIdx.x, bid = blockIdx.x;
  if (tid >= 256) return;
  const int c = bid * 4 + (tid >> 6), m = tid & 63;
  float ra = 0.f, za = 0.f, ia = 0.f, na = 0.f;
#pragma unroll
  for (int s = 0; s < 8; ++s) {
    const float* ps = part + (size_t)s * 3072 * 64;
    ra += ald(ps + (size_t)c * 64 + m);
    za += ald(ps + (size_t)(1024 + c) * 64 + m);
    float nv = ald(ps + (size_t)(2048 + c) * 64 + m);
    if (s < 4) ia += nv; else na += nv;
  }
  float r  = 1.f / (1.f + expf(-(ra + bx[c] + bm[c])));
  float zg = 1.f / (1.f + expf(-(za + bx[1024 + c] + bm[1024 + c])));
  float nn = tanhf(ia + bx[2048 + c] + r * (na + bm[2048 + c]));
  float hp = ald(h + (size_t)c * 64 + m);
  ast(h + (size_t)c * 64 + m, (1.f - zg) * nn + zg * hp);
}

// P5 (unchanged R9 design): C=1280 (1024 WhW1 | 256 Wh), 32 groups(40) x 8
// K-slices(128). Weights fp16: 5 scalar half loads/thread/chunk.
__device__ __forceinline__ void p5_mm(const __half* __restrict__ WhW1,
                                      const __half* __restrict__ Whd,
                                      const float* __restrict__ h2,
                                      float* __restrict__ part,
                                      float* __restrict__ sm) {
  float* sa = sm;            // [2][4096]
  float* sw = sm + 8192;     // [2][4096] rows of 64 (8 waves x 8 slots)
  const int tid = threadIdx.x;
  const int bid = blockIdx.x;
  const int g = bid >> 3, s = bid & 7;
  const int c0 = g * 40;
  const int k0 = s * 128;
  const float* A = h2 + (size_t)k0 * 64;
  const int kr = tid >> 3, ci = (tid & 7) * 5;
  const int w = tid >> 6, lane = tid & 63;
  float acc[5] = {0.f, 0.f, 0.f, 0.f, 0.f};
  unsigned long long av[4];
  float wl[5];
#define P5LD(chk, jj) \
  ({ int gc = c0 + ci + (jj); int krow = k0 + (chk) * 64 + kr; \
     __half2float((gc < 1024) ? WhW1[(size_t)krow * 1024 + gc] \
                              : Whd[(size_t)krow * 256 + (gc - 1024)]); })
  {
    const unsigned long long* Ab = (const unsigned long long*)A;
#pragma unroll
    for (int i = 0; i < 4; ++i) av[i] = ald64(Ab + tid + i * 512);
#pragma unroll
    for (int jj = 0; jj < 5; ++jj) wl[jj] = P5LD(0, jj);
#pragma unroll
    for (int i = 0; i < 4; ++i) {
      int jj = tid + i * 512;
      *(unsigned long long*)(sa + ((jj >> 5) << 6) + ((jj & 31) << 1)) = av[i];
    }
#pragma unroll
    for (int jj = 0; jj < 5; ++jj) sw[kr * 64 + (tid & 7) * 8 + jj] = wl[jj];
  }
  for (int ch = 0; ch < 2; ++ch) {
    const int buf = ch & 1;
    __syncthreads();
    if (ch < 1) {
      const unsigned long long* Ab = (const unsigned long long*)(A + 4096);
#pragma unroll
      for (int i = 0; i < 4; ++i) av[i] = ald64(Ab + tid + i * 512);
#pragma unroll
      for (int jj = 0; jj < 5; ++jj) wl[jj] = P5LD(1, jj);
    }
    const float* ap = sa + buf * 4096 + lane;
    const float* wp = sw + buf * 4096 + w * 8;
#pragma unroll 8
    for (int k = 0; k < 64; ++k) {
      float a = ap[k * 64];
      float4 w4 = *(const float4*)(wp + k * 64);
      float w1v = wp[k * 64 + 4];
      acc[0] = fmaf(a, w4.x, acc[0]); acc[1] = fmaf(a, w4.y, acc[1]);
      acc[2] = fmaf(a, w4.z, acc[2]); acc[3] = fmaf(a, w4.w, acc[3]);
      acc[4] = fmaf(a, w1v, acc[4]);
    }
    if (ch < 1) {
#pragma unroll
      for (int i = 0; i < 4; ++i) {
        int jj = tid + i * 512;
        *(unsigned long long*)(sa + 4096 + ((jj >> 5) << 6) + ((jj & 31) << 1)) = av[i];
      }
#pragma unroll
      for (int jj = 0; jj < 5; ++jj) sw[4096 + kr * 64 + (tid & 7) * 8 + jj] = wl[jj];
    }
  }
#undef P5LD
  float* pb = part + ((size_t)s * 1280 + c0 + w * 5) * 64 + lane;
#pragma unroll
  for (int j = 0; j < 5; ++j) ast(pb + (size_t)j * 64, acc[j]);
}

// P5 combine: t1 cols 0..1023 (tid<256), out cols 1024..1279 (tid 256..319).
__device__ __forceinline__ void p5b(const float* __restrict__ part,
                                    const float* __restrict__ bhw1,
                                    const float* __restrict__ bh,
                                    float* __restrict__ t1, float* __restrict__ out,
                                    int t) {
  const int tid = threadIdx.x, bid = blockIdx.x;
  if (tid < 256) {
    const int c = bid * 4 + (tid >> 6), m = tid & 63;
    float v = 0.f;
#pragma unroll
    for (int s = 0; s < 8; ++s) v += ald(part + ((size_t)s * 1280 + c) * 64 + m);
    ast(t1 + (size_t)c * 64 + m, fmaxf(v + bhw1[c], 0.f));
  } else if (tid < 320) {
    const int m = tid - 256, c2 = bid;
    float v = 0.f;
#pragma unroll
    for (int s = 0; s < 8; ++s) v += ald(part + ((size_t)s * 1280 + 1024 + c2) * 64 + m);
    out[(size_t)(m * TSTEP + t) * LATD + c2] = v + bh[c2];
  }
}

// P6: C=1024, 32 groups(32) x 8 K-slices(128). 4 ksubs x 128 thr;
// ksub owns 32 k; thread 4m x 4c (16 acc). Weights fp16 LDS [128][32]h at
// sm+8192 (2048 f). Per k: 1 b128 act + 1 b64 w = 2 LDS instr / 16 FMA.
__device__ __forceinline__ void p6_mm(const __half* __restrict__ w2h,
                                      const float* __restrict__ t1,
                                      float* __restrict__ part,
                                      float* __restrict__ sm) {
  const int tid = threadIdx.x;
  const int bid = blockIdx.x;
  const int g = bid >> 3, s = bid & 7;
  const int c0 = g * 32;
  const int k0 = s * 128;
  const float* A = t1 + (size_t)k0 * 64;

  {  // stage acts (4096 dw)
    const unsigned long long* Ab = (const unsigned long long*)A;
    unsigned long long* Sb = (unsigned long long*)sm;
#pragma unroll
    for (int i = 0; i < 8; ++i) Sb[tid + i * 512] = ald64(Ab + tid + i * 512);
  }
  {  // stage weights: 1024 8B-chunks (4 halves each)
    unsigned long long* Sw = (unsigned long long*)(sm + 8192);
#pragma unroll
    for (int i = 0; i < 2; ++i) {
      int q = tid + i * 512;
      int k = q >> 3, cq = q & 7;
      Sw[k * 8 + cq] =
          *(const unsigned long long*)(w2h + (size_t)(k0 + k) * 1024 + c0 + cq * 4);
    }
  }
  __syncthreads();

  const int ksub = tid >> 7, u = tid & 127;
  const int mq = u & 15, cg = u >> 4;
  float acc[16];
#pragma unroll
  for (int j = 0; j < 16; ++j) acc[j] = 0.f;
  const float* ap = sm + (size_t)(ksub * 32) * 64 + mq * 4;
  const __half* wp = (const __half*)(sm + 8192) + (size_t)(ksub * 32) * 32 + cg * 4;
#pragma unroll 4
  for (int k = 0; k < 32; ++k) {
    float4 a4 = *(const float4*)(ap + k * 64);
    union { unsigned long long v; __half h[4]; } ub;
    ub.v = *(const unsigned long long*)(wp + k * 32);
#pragma unroll
    for (int c = 0; c < 4; ++c) {
      float wf = __half2float(ub.h[c]);
      acc[c * 4 + 0] = fmaf(a4.x, wf, acc[c * 4 + 0]);
      acc[c * 4 + 1] = fmaf(a4.y, wf, acc[c * 4 + 1]);
      acc[c * 4 + 2] = fmaf(a4.z, wf, acc[c * 4 + 2]);
      acc[c * 4 + 3] = fmaf(a4.w, wf, acc[c * 4 + 3]);
    }
  }
  __syncthreads();
  float* red = sm;   // 3 * 2048 floats
  if (ksub) {
    float4* rp = (float4*)(red + (size_t)(ksub - 1) * 2048 + (size_t)u * 16);
#pragma unroll
    for (int j = 0; j < 4; ++j)
      rp[j] = make_float4(acc[4 * j], acc[4 * j + 1], acc[4 * j + 2], acc[4 * j + 3]);
  }
  __syncthreads();
  if (!ksub) {
#pragma unroll
    for (int q = 0; q < 3; ++q) {
      const float4* rp = (const float4*)(red + (size_t)q * 2048 + (size_t)u * 16);
#pragma unroll
      for (int j = 0; j < 4; ++j) {
        float4 r4 = rp[j];
        acc[4 * j] += r4.x; acc[4 * j + 1] += r4.y;
        acc[4 * j + 2] += r4.z; acc[4 * j + 3] += r4.w;
      }
    }
    float* pb0 = part + ((size_t)s * 1024 + c0 + cg * 4) * 64 + mq * 4;
#pragma unroll
    for (int c = 0; c < 4; ++c) {
      ast(pb0 + (size_t)c * 64 + 0, acc[c * 4 + 0]);
      ast(pb0 + (size_t)c * 64 + 1, acc[c * 4 + 1]);
      ast(pb0 + (size_t)c * 64 + 2, acc[c * 4 + 2]);
      ast(pb0 + (size_t)c * 64 + 3, acc[c * 4 + 3]);
    }
  }
}

__device__ __forceinline__ void p6b(const float* __restrict__ part,
                                    const float* __restrict__ b2,
                                    float* __restrict__ gin) {
  const int tid = threadIdx.x, bid = blockIdx.x;
  if (tid >= 256) return;
  const int c = bid * 4 + (tid >> 6), m = tid & 63;
  float v = 0.f;
#pragma unroll
  for (int s = 0; s < 8; ++s) v += ald(part + ((size_t)s * 1024 + c) * 64 + m);
  ast(gin + (size_t)c * 64 + m, fmaxf(v + b2[c], 0.f));
}

__global__ __launch_bounds__(512, 1) void persist(P p) {
  cg::grid_group grid = cg::this_grid();
  // 112 KB: gru acts [256][64] f32 (16384 f) | planeA [256][64]h (8192 f) |
  // planeB [256][32]h (4096 f). p5 uses first 16384 f; p6 first 10240 f.
  __shared__ float sm[28672];
  unsigned ep = 0;

  // ---- prologue (4 slow cg syncs flush prologue's normal stores) ----
  if (blockIdx.x == 0) {
    for (int i = threadIdx.x; i < 1024; i += 512) p.bar[i] = 0u;
  }
  if (threadIdx.x < 64) {  // z transpose -> h1 region (consumed pre-overwrite)
    int i = blockIdx.x * 64 + threadIdx.x;
    int m = i >> 8, l = i & 255;
    p.h1[l * 64 + m] = p.z[i];
  }
  matmat<1024, 1024, 8>(p.Wv, p.Wo, p.part);            // Wvo (fp32 temp)
  vecmat(p.bh, p.w1, p.b1, p.bhw1, 256, 1024, 0, 2);
  vecmat(p.bv, p.Wo, p.bo, p.bvo, 1024, 1024, 2, 2);
  cvt_copy(p.Whh0, p.Whh0h, 786432);                    // raw weights -> fp16
  cvt_copy(p.Wih1, p.Wih1h, 786432);
  cvt_copy(p.Whh1, p.Whh1h, 786432);
  cvt_copy(p.w2,   p.w2h,   262144);
  cvt_copy(p.Wh,   p.Whh,   65536);
  grid.sync();
  matmat<1024, 3072, 24>(p.part, p.Wih0, p.Wvoihh);     // Wvoih -> fp16 direct
  matmat<256, 1024, 8>(p.Wh, p.w1, p.WhW1h);            // WhW1 -> fp16 direct
  vecmat(p.bvo, p.Wih0, p.bih0, p.bfold, 1024, 3072, 0, 6);
  grid.sync();
  gemv1024(p.h1, p.w1, p.b1, 256, 1, p.t1, nullptr, nullptr, sm);
  grid.sync();
  gemv1024(p.t1, p.w2, p.b2, 1024, 0, p.h1, p.h2, p.gin, sm);
  grid.sync();

  // ---- time loop: 8 fence-free phases/step ----
  for (int t = 0; t < TSTEP; ++t) {
    gru_mm(p.Wvoihh, p.gin, p.Whh0h, p.h1, p.part, sm); fastbar(p.bar, ep);
    gru_comb(p.part, p.bfold, p.bhh0, p.h1);            fastbar(p.bar, ep);
    gru_mm(p.Wih1h, p.h1, p.Whh1h, p.h2, p.part, sm);   fastbar(p.bar, ep);
    gru_comb(p.part, p.bih1, p.bhh1, p.h2);             fastbar(p.bar, ep);
    p5_mm(p.WhW1h, p.Whh, p.h2, p.part, sm);            fastbar(p.bar, ep);
    p5b(p.part, p.bhw1, p.bh, p.t1, p.out, t);          fastbar(p.bar, ep);
    p6_mm(p.w2h, p.t1, p.part, sm);                     fastbar(p.bar, ep);
    p6b(p.part, p.b2, p.gin);                           fastbar(p.bar, ep);
  }
}

// ---------------------------------------------------------------------------
// Fallback path (round-2 verified multi-kernel, fp32 — unchanged).
// ---------------------------------------------------------------------------
__global__ void fb_transpose(const float* __restrict__ z, float* __restrict__ zT) {
  int i = blockIdx.x * 256 + threadIdx.x;
  int m = i >> 8, l = i & 255;
  zT[l * 64 + m] = z[i];
}
__global__ void fb_copy2(const float* __restrict__ s, float* __restrict__ d1,
                         float* __restrict__ d2) {
  int i = blockIdx.x * 256 + threadIdx.x;
  float v = s[i]; d1[i] = v; d2[i] = v;
}
template <int ACT>
__global__ void fb_gemm(const float* __restrict__ A_T, const float* __restrict__ W,
                        const float* __restrict__ bias, float* __restrict__ C_T,
                        int K, int N, float* __restrict__ outp, int tstep) {
  const int m = threadIdx.x & 63;
  const int wv = threadIdx.x >> 6;
  const int c = blockIdx.x * 4 + wv;
  float acc0 = 0.f, acc1 = 0.f;
  const float* ap = A_T + m;
  const float* wp = W + c;
#pragma unroll 4
  for (int k = 0; k + 1 < K; k += 2) {
    acc0 = fmaf(ap[k * 64], wp[(size_t)k * N], acc0);
    acc1 = fmaf(ap[(k + 1) * 64], wp[(size_t)(k + 1) * N], acc1);
  }
  float v0 = acc0 + acc1 + bias[c];
  if (ACT) v0 = fmaxf(v0, 0.f);
  C_T[c * 64 + m] = v0;
  if (outp != nullptr) outp[(size_t)(m * TSTEP + tstep) * LATD + c] = v0;
}
__global__ void fb_gru(const float* __restrict__ xT, const float* __restrict__ hT,
                       const float* __restrict__ Wih, const float* __restrict__ Whh,
                       const float* __restrict__ bih, const float* __restrict__ bhh,
                       float* __restrict__ hnT) {
  const int m = threadIdx.x & 63;
  const int wv = threadIdx.x >> 6;
  const int c = blockIdx.x * 4 + wv;
  float racc = 0, zacc = 0, iacc = 0, nacc = 0;
  const float* xp = xT + m;
  const float* hp = hT + m;
  const float* wi = Wih + c;
  const float* wh = Whh + c;
#pragma unroll 2
  for (int k = 0; k < 1024; ++k) {
    float a = xp[k * 64];
    float h = hp[k * 64];
    const float* wik = wi + (size_t)k * 3072;
    const float* whk = wh + (size_t)k * 3072;
    racc = fmaf(a, wik[0], racc); racc = fmaf(h, whk[0], racc);
    zacc = fmaf(a, wik[1024], zacc); zacc = fmaf(h, whk[1024], zacc);
    iacc = fmaf(a, wik[2048], iacc);
    nacc = fmaf(h, whk[2048], nacc);
  }
  float r = 1.f / (1.f + expf(-(racc + bih[c] + bhh[c])));
  float zg = 1.f / (1.f + expf(-(zacc + bih[1024 + c] + bhh[1024 + c])));
  float nn = tanhf(iacc + bih[2048 + c] + r * (nacc + bhh[2048 + c]));
  hnT[c * 64 + m] = (1.f - zg) * nn + zg * hT[c * 64 + m];
}

extern "C" void kernel_launch(void* const* d_in, const int* in_sizes, int n_in,
                              void* d_out, int out_size, void* d_ws, size_t ws_size,
                              hipStream_t stream) {
  const float* z_start = (const float*)d_in[0];
  const float* w1 = (const float*)d_in[2];
  const float* b1 = (const float*)d_in[3];
  const float* w2 = (const float*)d_in[4];
  const float* b2 = (const float*)d_in[5];
  const float* Wv = (const float*)d_in[10];
  const float* bv = (const float*)d_in[11];
  const float* Wo = (const float*)d_in[12];
  const float* bo = (const float*)d_in[13];
  const float* Wih0 = (const float*)d_in[14];
  const float* Whh0 = (const float*)d_in[15];
  const float* bih0 = (const float*)d_in[16];
  const float* bhh0 = (const float*)d_in[17];
  const float* Wih1 = (const float*)d_in[18];
  const float* Whh1 = (const float*)d_in[19];
  const float* bih1 = (const float*)d_in[20];
  const float* bhh1 = (const float*)d_in[21];
  const float* Wh = (const float*)d_in[22];
  const float* bh = (const float*)d_in[23];
  float* out = (float*)d_out;
  float* ws = (float*)d_ws;

  // floats: 4x1572864 (Wvoih_h,Whh0_h,Wih1_h,Whh1_h) + part 1572864 +
  // 524288x2 (WhW1_h,w2_h) + 131072 (Wh_h) + 4x65536 acts + 5120 small + 1024
  const size_t need = (size_t)9312256 * 4;
  if (ws_size >= need) {
    P p;
    p.z = z_start; p.w1 = w1; p.b1 = b1; p.w2 = w2; p.b2 = b2;
    p.Wv = Wv; p.bv = bv; p.Wo = Wo; p.bo = bo;
    p.Wih0 = Wih0; p.Whh0 = Whh0; p.bih0 = bih0; p.bhh0 = bhh0;
    p.Wih1 = Wih1; p.Whh1 = Whh1; p.bih1 = bih1; p.bhh1 = bhh1;
    p.Wh = Wh; p.bh = bh; p.out = out;
    float* q = ws;
    p.Wvoihh = (__half*)q; q += 1572864;   // 1024x3072 halves
    p.Whh0h  = (__half*)q; q += 1572864;
    p.Wih1h  = (__half*)q; q += 1572864;
    p.Whh1h  = (__half*)q; q += 1572864;
    p.WhW1h  = (__half*)q; q += 524288;    // 1024x1024 halves
    p.Whh    = (__half*)q; q += 131072;    // 1024x256 halves
    p.w2h    = (__half*)q; q += 524288;
    p.part = q; q += 1572864;   // Wvo fp32 temp in prologue; partials in loop
    p.gin = q; q += 65536;
    p.h1 = q; q += 65536;       // also zT during prologue
    p.h2 = q; q += 65536;
    p.t1 = q; q += 65536;
    p.bvo = q; q += 1024;
    p.bfold = q; q += 3072;
    p.bhw1 = q; q += 1024;
    p.bar = (unsigned*)q; q += 1024;
    void* args[] = { &p };
    hipError_t e = hipLaunchCooperativeKernel((const void*)persist, dim3(256),
                                              dim3(512), args, 0, stream);
    if (e == hipSuccess) return;
  }

  // -------- fallback: verified round-2 path --------
  float* zsT = ws;
  float* vT = zsT + 16384;
  float* xaT = vT + 65536;
  float* t1T = xaT + 65536;
  float* ginT = t1T + 65536;
  float* nzT = ginT + 65536;
  float* h1T = nzT + 16384;
  float* h2T = h1T + 2 * 65536;

  fb_transpose<<<64, 256, 0, stream>>>(z_start, zsT);
  fb_gemm<1><<<256, 256, 0, stream>>>(zsT, w1, b1, t1T, 256, 1024, nullptr, 0);
  fb_gemm<0><<<256, 256, 0, stream>>>(t1T, w2, b2, h1T, 1024, 1024, nullptr, 0);
  fb_copy2<<<256, 256, 0, stream>>>(h1T, h2T, ginT);
  for (int t = 0; t < TSTEP; ++t) {
    float* h1p = h1T + (t & 1) * 65536;
    float* h1n = h1T + ((t + 1) & 1) * 65536;
    float* h2p = h2T + (t & 1) * 65536;
    float* h2n = h2T + ((t + 1) & 1) * 65536;
    fb_gemm<0><<<256, 256, 0, stream>>>(ginT, Wv, bv, vT, 1024, 1024, nullptr, 0);
    fb_gemm<0><<<256, 256, 0, stream>>>(vT, Wo, bo, xaT, 1024, 1024, nullptr, 0);
    fb_gru<<<256, 256, 0, stream>>>(xaT, h1p, Wih0, Whh0, bih0, bhh0, h1n);
    fb_gru<<<256, 256, 0, stream>>>(h1n, h2p, Wih1, Whh1, bih1, bhh1, h2n);
    fb_gemm<0><<<64, 256, 0, stream>>>(h2n, Wh, bh, nzT, 1024, 256, out, t);
    fb_gemm<1><<<256, 256, 0, stream>>>(nzT, w1, b1, t1T, 256, 1024, nullptr, 0);
    fb_gemm<1><<<256, 256, 0, stream>>>(t1T, w2, b2, ginT, 1024, 1024, nullptr, 0);
  }
}

// Round 5
// 12286.469 us; speedup vs baseline: 1.1949x; 1.0883x over previous
//
#include <hip/hip_runtime.h>
#include <hip/hip_cooperative_groups.h>
#include <hip/hip_fp16.h>

namespace cg = cooperative_groups;

#define TSTEP 128
#define LATD 256

// ---------------------------------------------------------------------------
// R12 = R11 + dense part-store epilogue. R11 counters: WRITE_SIZE 3.4x R9
// (62 MB/step; 24 scalar 4B sc1 stores/thread at 16B stride -> ~4x write
// amplification on the write-through path) and LDS_BANK_CONFLICT 24x (tree
// reduce at u*48-float stride -> 16-way conflicts). Fix: all 4 ksubs write
// acc tiles to LDS in PART-LINEAR layout; then 512 threads K-sum + store
// part densely (pass p: 8B store at p*1024 + tid*2 -> 4KB contiguous per
// instruction). Same for p6. Store instrs 4x fewer, write traffic 3.4x less,
// reduce conflicts gone. FMA loops, p5, combines, fastbar, prologue, phases:
// UNCHANGED from R11 (verified, absmax 9.8e-4).
// Folds (verified R3-R11): Wvoih=(Wv@Wo)@Wih0, bfold=(bv@Wo+bo)@Wih0+bih0,
// WhW1=Wh@w1, bhw1=bh@w1+b1. Step = 8 phases.
// ---------------------------------------------------------------------------

typedef __attribute__((ext_vector_type(2))) unsigned long long u64x2;

struct P {
  const float *z, *w1, *b1, *w2, *b2, *Wv, *bv, *Wo, *bo;
  const float *Wih0, *Whh0, *bih0, *bhh0, *Wih1, *Whh1, *bih1, *bhh1, *Wh, *bh;
  float *out;
  __half *Wvoihh, *Whh0h, *Wih1h, *Whh1h, *WhW1h, *Whh, *w2h;
  float *part, *gin, *h1, *h2, *t1, *bvo, *bfold, *bhw1;
  unsigned *bar;   // leaves at i*32 (i<16), root at 512, flag at 544
};

__device__ __forceinline__ float ald(const float* p) {
  return __hip_atomic_load((float*)p, __ATOMIC_RELAXED, __HIP_MEMORY_SCOPE_AGENT);
}
__device__ __forceinline__ void ast(float* p, float v) {
  __hip_atomic_store(p, v, __ATOMIC_RELAXED, __HIP_MEMORY_SCOPE_AGENT);
}
__device__ __forceinline__ unsigned long long ald64(const unsigned long long* p) {
  return __hip_atomic_load((unsigned long long*)p, __ATOMIC_RELAXED,
                           __HIP_MEMORY_SCOPE_AGENT);
}
__device__ __forceinline__ void ast64(unsigned long long* p, unsigned long long v) {
  __hip_atomic_store(p, v, __ATOMIC_RELAXED, __HIP_MEMORY_SCOPE_AGENT);
}

// 4 packed halves -> float4 (staging helpers).
__device__ __forceinline__ float4 h4f(unsigned long long u) {
  union { unsigned long long q; __half h[4]; } c; c.q = u;
  return make_float4(__half2float(c.h[0]), __half2float(c.h[1]),
                     __half2float(c.h[2]), __half2float(c.h[3]));
}
__device__ __forceinline__ unsigned long long f4h4(float4 v) {
  union { unsigned long long q; __half h[4]; } c;
  c.h[0] = __float2half(v.x); c.h[1] = __float2half(v.y);
  c.h[2] = __float2half(v.z); c.h[3] = __float2half(v.w);
  return c.q;
}

// Fence-free hierarchical grid barrier (semantics proven in R7).
__device__ __forceinline__ void fastbar(unsigned* bar, unsigned& ep) {
  ++ep;
  __atomic_signal_fence(__ATOMIC_SEQ_CST);
  __builtin_amdgcn_s_waitcnt(0);
  __atomic_signal_fence(__ATOMIC_SEQ_CST);
  __syncthreads();
  if (threadIdx.x == 0) {
    unsigned* leaf = bar + (blockIdx.x & 15u) * 32u;
    unsigned a = atomicAdd(leaf, 1u);
    if (a == ep * 16u - 1u) {
      unsigned r = atomicAdd(bar + 512, 1u);
      if (r == ep * 16u - 1u)
        __hip_atomic_store(bar + 544, ep, __ATOMIC_RELAXED, __HIP_MEMORY_SCOPE_AGENT);
    }
    while (__hip_atomic_load(bar + 544, __ATOMIC_RELAXED, __HIP_MEMORY_SCOPE_AGENT) < ep)
      __builtin_amdgcn_s_sleep(1);
  }
  __syncthreads();
}

// ---- prologue helpers (256 blocks x 512 threads) --------------------------
__device__ __forceinline__ void stv(float* p, float v) { *p = v; }
__device__ __forceinline__ void stv(__half* p, float v) { *p = __float2half(v); }

template <int J, int N, int CPT, typename OT>
__device__ void matmat(const float* __restrict__ A, const float* __restrict__ B,
                       OT* __restrict__ C) {
  const int tid = threadIdx.x;
  const int r = blockIdx.x * 4 + (tid >> 7);
  const int c0 = tid & 127;
  float acc[CPT];
#pragma unroll
  for (int i = 0; i < CPT; ++i) acc[i] = 0.f;
  const float* ar = A + (size_t)r * J;
#pragma unroll 2
  for (int j = 0; j < J; ++j) {
    float av = ar[j];
    const float* br = B + (size_t)j * N + c0;
#pragma unroll
    for (int i = 0; i < CPT; ++i) acc[i] = fmaf(av, br[i * 128], acc[i]);
  }
  OT* cr = C + (size_t)r * N + c0;
#pragma unroll
  for (int i = 0; i < CPT; ++i) stv(cr + (size_t)i * 128, acc[i]);
}

// fp32 -> fp16 copy, float4 granularity. n4 = element_count/4.
__device__ void cvt_copy(const float* __restrict__ s, __half* __restrict__ d,
                         int n4) {
  for (int i = (int)(blockIdx.x * 512u + threadIdx.x); i < n4; i += 131072)
    *(unsigned long long*)(d + (size_t)i * 4) = f4h4(*(const float4*)(s + (size_t)i * 4));
}

__device__ void vecmat(const float* __restrict__ v, const float* __restrict__ M,
                       const float* __restrict__ badd, float* __restrict__ outv,
                       int J, int N, int blk0, int nblk) {
  int b = (int)blockIdx.x;
  if (b < blk0 || b >= blk0 + nblk) return;
  int gid = (b - blk0) * 512 + threadIdx.x;
  if (gid >= N) return;
  float acc = 0.f;
#pragma unroll 4
  for (int j = 0; j < J; ++j) acc = fmaf(v[j], M[(size_t)j * N + gid], acc);
  outv[gid] = acc + badd[gid];
}

__device__ void gemv1024(const float* __restrict__ A, const float* __restrict__ W,
                         const float* __restrict__ bias, int K, int relu,
                         float* __restrict__ C, float* __restrict__ C2,
                         float* __restrict__ C3, float* red) {
  const int tid = threadIdx.x;
  const int m = tid & 63, w = tid >> 6;
  const int j = w & 3, hh = w >> 2;
  const int c = blockIdx.x * 4 + j;
  const int kh = K >> 1;
  const float* a = A + m + (hh * kh) * 64;
  const float* wp = W + c + (size_t)(hh * kh) * 1024;
  float acc = 0.f;
#pragma unroll 8
  for (int k = 0; k < kh; ++k) acc = fmaf(a[k * 64], wp[(size_t)k * 1024], acc);
  if (hh) red[j * 64 + m] = acc;
  __syncthreads();
  if (!hh) {
    float v = acc + red[j * 64 + m] + bias[c];
    if (relu) v = fmaxf(v, 0.f);
    C[c * 64 + m] = v;
    if (C2) C2[c * 64 + m] = v;
    if (C3) C3[c * 64 + m] = v;
  }
  __syncthreads();
}

// ---- GRU matmul: 256 blocks = 32 col-groups(96) x 8 K-slices(256) ---------
// 4 ksubs x 128 thr; ksub owns 64 k. Thread: 4m x 12c tile (48 acc).
// LDS: acts fp32 [256][64] at sm[0] (16384 f); planeA [256][64]h at
// sm+16384 (8192 f); planeB [256][32]h at sm+24576 (4096 f) = 28672 f.
// Per k: 1 b128 act + 1 b128 wA + 1 b64 wB = 3 LDS instr / 48 FMA.
// Epilogue (R12): 4 LDS regions [ksub][6144] part-linear; 512 thr K-sum
// + dense 8B sc1 stores (pass p: p*1024 + tid*2 -> 4KB/instr contiguous).
__device__ __forceinline__ void gru_mm(const __half* __restrict__ Wx,
                                       const float* __restrict__ actx,
                                       const __half* __restrict__ Whm,
                                       const float* __restrict__ acth,
                                       float* __restrict__ part,
                                       float* __restrict__ sm) {
  const int tid = threadIdx.x;
  const int bid = blockIdx.x;
  const int g = bid >> 3, s = bid & 7;
  const int c0 = g * 96;
  const int k0 = (s & 3) * 256;
  const __half* W = (s < 4 ? Wx : Whm);
  const float* A = (s < 4 ? actx : acth) + (size_t)k0 * 64;

  // ---- stage acts (8192 dw) ----
  {
    const unsigned long long* Ab = (const unsigned long long*)A;
    unsigned long long* Sb = (unsigned long long*)sm;
#pragma unroll
    for (int i = 0; i < 16; ++i) Sb[tid + i * 512] = ald64(Ab + tid + i * 512);
  }
  // ---- stage weights fp16 -> planes (thread: k=tid>>1, 48 halves) ----
  {
    const int k = tid >> 1, hr = tid & 1;
    const unsigned long long* Wr =
        (const unsigned long long*)(W + (size_t)(k0 + k) * 3072 + c0) + hr * 12;
    unsigned long long* pa = (unsigned long long*)(sm + 16384) + k * 16 + hr * 8;
    unsigned long long* pb = (unsigned long long*)(sm + 24576) + k * 8 + hr * 4;
#pragma unroll
    for (int j = 0; j < 4; ++j) {
      unsigned long long q0 = Wr[j * 3];
      unsigned long long q1 = Wr[j * 3 + 1];
      unsigned long long q2 = Wr[j * 3 + 2];
      pa[j * 2] = q0; pa[j * 2 + 1] = q1; pb[j] = q2;
    }
  }
  __syncthreads();

  const int ksub = tid >> 7, u = tid & 127;
  const int mq = u & 15, cg = u >> 4;
  float acc[48];
#pragma unroll
  for (int j = 0; j < 48; ++j) acc[j] = 0.f;
  const float* ap = sm + (size_t)(ksub * 64) * 64 + mq * 4;
  const __half* wa = (const __half*)(sm + 16384) + (size_t)(ksub * 64) * 64 + cg * 8;
  const __half* wb = (const __half*)(sm + 24576) + (size_t)(ksub * 64) * 32 + cg * 4;
#pragma unroll 2
  for (int k = 0; k < 64; ++k) {
    float4 a4 = *(const float4*)(ap + k * 64);
    union { u64x2 v; __half h[8]; } ua;
    ua.v = *(const u64x2*)(wa + k * 64);
    union { unsigned long long v; __half h[4]; } ub;
    ub.v = *(const unsigned long long*)(wb + k * 32);
#pragma unroll
    for (int c = 0; c < 8; ++c) {
      float wf = __half2float(ua.h[c]);
      acc[c * 4 + 0] = fmaf(a4.x, wf, acc[c * 4 + 0]);
      acc[c * 4 + 1] = fmaf(a4.y, wf, acc[c * 4 + 1]);
      acc[c * 4 + 2] = fmaf(a4.z, wf, acc[c * 4 + 2]);
      acc[c * 4 + 3] = fmaf(a4.w, wf, acc[c * 4 + 3]);
    }
#pragma unroll
    for (int c = 0; c < 4; ++c) {
      float wf = __half2float(ub.h[c]);
      acc[32 + c * 4 + 0] = fmaf(a4.x, wf, acc[32 + c * 4 + 0]);
      acc[32 + c * 4 + 1] = fmaf(a4.y, wf, acc[32 + c * 4 + 1]);
      acc[32 + c * 4 + 2] = fmaf(a4.z, wf, acc[32 + c * 4 + 2]);
      acc[32 + c * 4 + 3] = fmaf(a4.w, wf, acc[32 + c * 4 + 3]);
    }
  }
  // ---- R12 epilogue: all ksubs -> LDS (part-linear), dense K-sum+store ----
  __syncthreads();   // acts/weights consumption complete
  float* red = sm;   // 4 regions x 6144 floats, layout = col_local*64 + m
  {
    float* rp = red + (size_t)ksub * 6144 + (size_t)cg * 12 * 64 + mq * 4;
#pragma unroll
    for (int c = 0; c < 8; ++c)
      *(float4*)(rp + (size_t)c * 64) =
          make_float4(acc[c * 4], acc[c * 4 + 1], acc[c * 4 + 2], acc[c * 4 + 3]);
#pragma unroll
    for (int c = 0; c < 4; ++c)
      *(float4*)(rp + (size_t)(8 + c) * 64) =
          make_float4(acc[32 + c * 4], acc[32 + c * 4 + 1],
                      acc[32 + c * 4 + 2], acc[32 + c * 4 + 3]);
  }
  __syncthreads();
  {
    float* pbase = part + ((size_t)s * 3072 + c0) * 64;   // 6144 contiguous
#pragma unroll
    for (int ps5 = 0; ps5 < 6; ++ps5) {
      int idx = ps5 * 1024 + tid * 2;
      float2 a0 = *(const float2*)(red + idx);
      float2 a1 = *(const float2*)(red + 6144 + idx);
      float2 a2 = *(const float2*)(red + 12288 + idx);
      float2 a3 = *(const float2*)(red + 18432 + idx);
      union { float2 f; unsigned long long q; } uo;
      uo.f.x = (a0.x + a1.x) + (a2.x + a3.x);
      uo.f.y = (a0.y + a1.y) + (a2.y + a3.y);
      ast64((unsigned long long*)(pbase + idx), uo.q);
    }
  }
}

// GRU combine: 8 K-slices (0-3 x-part, 4-7 h-part). 256 blocks, 256 thr.
__device__ __forceinline__ void gru_comb(const float* __restrict__ part,
                                         const float* __restrict__ bx,
                                         const float* __restrict__ bm,
                                         float* __restrict__ h) {
  const int tid = threadIdx.x, bid = blockIdx.x;
  if (tid >= 256) return;
  const int c = bid * 4 + (tid >> 6), m = tid & 63;
  float ra = 0.f, za = 0.f, ia = 0.f, na = 0.f;
#pragma unroll
  for (int s = 0; s < 8; ++s) {
    const float* ps = part + (size_t)s * 3072 * 64;
    ra += ald(ps + (size_t)c * 64 + m);
    za += ald(ps + (size_t)(1024 + c) * 64 + m);
    float nv = ald(ps + (size_t)(2048 + c) * 64 + m);
    if (s < 4) ia += nv; else na += nv;
  }
  float r  = 1.f / (1.f + expf(-(ra + bx[c] + bm[c])));
  float zg = 1.f / (1.f + expf(-(za + bx[1024 + c] + bm[1024 + c])));
  float nn = tanhf(ia + bx[2048 + c] + r * (na + bm[2048 + c]));
  float hp = ald(h + (size_t)c * 64 + m);
  ast(h + (size_t)c * 64 + m, (1.f - zg) * nn + zg * hp);
}

// P5 (unchanged R9 design): C=1280 (1024 WhW1 | 256 Wh), 32 groups(40) x 8
// K-slices(128). Weights fp16: 5 scalar half loads/thread/chunk.
__device__ __forceinline__ void p5_mm(const __half* __restrict__ WhW1,
                                      const __half* __restrict__ Whd,
                                      const float* __restrict__ h2,
                                      float* __restrict__ part,
                                      float* __restrict__ sm) {
  float* sa = sm;            // [2][4096]
  float* sw = sm + 8192;     // [2][4096] rows of 64 (8 waves x 8 slots)
  const int tid = threadIdx.x;
  const int bid = blockIdx.x;
  const int g = bid >> 3, s = bid & 7;
  const int c0 = g * 40;
  const int k0 = s * 128;
  const float* A = h2 + (size_t)k0 * 64;
  const int kr = tid >> 3, ci = (tid & 7) * 5;
  const int w = tid >> 6, lane = tid & 63;
  float acc[5] = {0.f, 0.f, 0.f, 0.f, 0.f};
  unsigned long long av[4];
  float wl[5];
#define P5LD(chk, jj) \
  ({ int gc = c0 + ci + (jj); int krow = k0 + (chk) * 64 + kr; \
     __half2float((gc < 1024) ? WhW1[(size_t)krow * 1024 + gc] \
                              : Whd[(size_t)krow * 256 + (gc - 1024)]); })
  {
    const unsigned long long* Ab = (const unsigned long long*)A;
#pragma unroll
    for (int i = 0; i < 4; ++i) av[i] = ald64(Ab + tid + i * 512);
#pragma unroll
    for (int jj = 0; jj < 5; ++jj) wl[jj] = P5LD(0, jj);
#pragma unroll
    for (int i = 0; i < 4; ++i) {
      int jj = tid + i * 512;
      *(unsigned long long*)(sa + ((jj >> 5) << 6) + ((jj & 31) << 1)) = av[i];
    }
#pragma unroll
    for (int jj = 0; jj < 5; ++jj) sw[kr * 64 + (tid & 7) * 8 + jj] = wl[jj];
  }
  for (int ch = 0; ch < 2; ++ch) {
    const int buf = ch & 1;
    __syncthreads();
    if (ch < 1) {
      const unsigned long long* Ab = (const unsigned long long*)(A + 4096);
#pragma unroll
      for (int i = 0; i < 4; ++i) av[i] = ald64(Ab + tid + i * 512);
#pragma unroll
      for (int jj = 0; jj < 5; ++jj) wl[jj] = P5LD(1, jj);
    }
    const float* ap = sa + buf * 4096 + lane;
    const float* wp = sw + buf * 4096 + w * 8;
#pragma unroll 8
    for (int k = 0; k < 64; ++k) {
      float a = ap[k * 64];
      float4 w4 = *(const float4*)(wp + k * 64);
      float w1v = wp[k * 64 + 4];
      acc[0] = fmaf(a, w4.x, acc[0]); acc[1] = fmaf(a, w4.y, acc[1]);
      acc[2] = fmaf(a, w4.z, acc[2]); acc[3] = fmaf(a, w4.w, acc[3]);
      acc[4] = fmaf(a, w1v, acc[4]);
    }
    if (ch < 1) {
#pragma unroll
      for (int i = 0; i < 4; ++i) {
        int jj = tid + i * 512;
        *(unsigned long long*)(sa + 4096 + ((jj >> 5) << 6) + ((jj & 31) << 1)) = av[i];
      }
#pragma unroll
      for (int jj = 0; jj < 5; ++jj) sw[4096 + kr * 64 + (tid & 7) * 8 + jj] = wl[jj];
    }
  }
#undef P5LD
  float* pb = part + ((size_t)s * 1280 + c0 + w * 5) * 64 + lane;
#pragma unroll
  for (int j = 0; j < 5; ++j) ast(pb + (size_t)j * 64, acc[j]);
}

// P5 combine: t1 cols 0..1023 (tid<256), out cols 1024..1279 (tid 256..319).
__device__ __forceinline__ void p5b(const float* __restrict__ part,
                                    const float* __restrict__ bhw1,
                                    const float* __restrict__ bh,
                                    float* __restrict__ t1, float* __restrict__ out,
                                    int t) {
  const int tid = threadIdx.x, bid = blockIdx.x;
  if (tid < 256) {
    const int c = bid * 4 + (tid >> 6), m = tid & 63;
    float v = 0.f;
#pragma unroll
    for (int s = 0; s < 8; ++s) v += ald(part + ((size_t)s * 1280 + c) * 64 + m);
    ast(t1 + (size_t)c * 64 + m, fmaxf(v + bhw1[c], 0.f));
  } else if (tid < 320) {
    const int m = tid - 256, c2 = bid;
    float v = 0.f;
#pragma unroll
    for (int s = 0; s < 8; ++s) v += ald(part + ((size_t)s * 1280 + 1024 + c2) * 64 + m);
    out[(size_t)(m * TSTEP + t) * LATD + c2] = v + bh[c2];
  }
}

// P6: C=1024, 32 groups(32) x 8 K-slices(128). 4 ksubs x 128 thr;
// ksub owns 32 k; thread 4m x 4c (16 acc). Weights fp16 LDS [128][32]h at
// sm+8192 (2048 f). Per k: 1 b128 act + 1 b64 w = 2 LDS instr / 16 FMA.
// Epilogue (R12): 4 LDS regions [ksub][2048] part-linear; dense 8B stores.
__device__ __forceinline__ void p6_mm(const __half* __restrict__ w2h,
                                      const float* __restrict__ t1,
                                      float* __restrict__ part,
                                      float* __restrict__ sm) {
  const int tid = threadIdx.x;
  const int bid = blockIdx.x;
  const int g = bid >> 3, s = bid & 7;
  const int c0 = g * 32;
  const int k0 = s * 128;
  const float* A = t1 + (size_t)k0 * 64;

  {  // stage acts (4096 dw)
    const unsigned long long* Ab = (const unsigned long long*)A;
    unsigned long long* Sb = (unsigned long long*)sm;
#pragma unroll
    for (int i = 0; i < 8; ++i) Sb[tid + i * 512] = ald64(Ab + tid + i * 512);
  }
  {  // stage weights: 1024 8B-chunks (4 halves each)
    unsigned long long* Sw = (unsigned long long*)(sm + 8192);
#pragma unroll
    for (int i = 0; i < 2; ++i) {
      int q = tid + i * 512;
      int k = q >> 3, cq = q & 7;
      Sw[k * 8 + cq] =
          *(const unsigned long long*)(w2h + (size_t)(k0 + k) * 1024 + c0 + cq * 4);
    }
  }
  __syncthreads();

  const int ksub = tid >> 7, u = tid & 127;
  const int mq = u & 15, cg = u >> 4;
  float acc[16];
#pragma unroll
  for (int j = 0; j < 16; ++j) acc[j] = 0.f;
  const float* ap = sm + (size_t)(ksub * 32) * 64 + mq * 4;
  const __half* wp = (const __half*)(sm + 8192) + (size_t)(ksub * 32) * 32 + cg * 4;
#pragma unroll 4
  for (int k = 0; k < 32; ++k) {
    float4 a4 = *(const float4*)(ap + k * 64);
    union { unsigned long long v; __half h[4]; } ub;
    ub.v = *(const unsigned long long*)(wp + k * 32);
#pragma unroll
    for (int c = 0; c < 4; ++c) {
      float wf = __half2float(ub.h[c]);
      acc[c * 4 + 0] = fmaf(a4.x, wf, acc[c * 4 + 0]);
      acc[c * 4 + 1] = fmaf(a4.y, wf, acc[c * 4 + 1]);
      acc[c * 4 + 2] = fmaf(a4.z, wf, acc[c * 4 + 2]);
      acc[c * 4 + 3] = fmaf(a4.w, wf, acc[c * 4 + 3]);
    }
  }
  // ---- R12 epilogue ----
  __syncthreads();
  float* red = sm;   // 4 regions x 2048 floats, layout = col_local*64 + m
  {
    float* rp = red + (size_t)ksub * 2048 + (size_t)cg * 4 * 64 + mq * 4;
#pragma unroll
    for (int c = 0; c < 4; ++c)
      *(float4*)(rp + (size_t)c * 64) =
          make_float4(acc[c * 4], acc[c * 4 + 1], acc[c * 4 + 2], acc[c * 4 + 3]);
  }
  __syncthreads();
  {
    float* pbase = part + ((size_t)s * 1024 + c0) * 64;   // 2048 contiguous
#pragma unroll
    for (int ps5 = 0; ps5 < 2; ++ps5) {
      int idx = ps5 * 1024 + tid * 2;
      float2 a0 = *(const float2*)(red + idx);
      float2 a1 = *(const float2*)(red + 2048 + idx);
      float2 a2 = *(const float2*)(red + 4096 + idx);
      float2 a3 = *(const float2*)(red + 6144 + idx);
      union { float2 f; unsigned long long q; } uo;
      uo.f.x = (a0.x + a1.x) + (a2.x + a3.x);
      uo.f.y = (a0.y + a1.y) + (a2.y + a3.y);
      ast64((unsigned long long*)(pbase + idx), uo.q);
    }
  }
}

__device__ __forceinline__ void p6b(const float* __restrict__ part,
                                    const float* __restrict__ b2,
                                    float* __restrict__ gin) {
  const int tid = threadIdx.x, bid = blockIdx.x;
  if (tid >= 256) return;
  const int c = bid * 4 + (tid >> 6), m = tid & 63;
  float v = 0.f;
#pragma unroll
  for (int s = 0; s < 8; ++s) v += ald(part + ((size_t)s * 1024 + c) * 64 + m);
  ast(gin + (size_t)c * 64 + m, fmaxf(v + b2[c], 0.f));
}

__global__ __launch_bounds__(512, 1) void persist(P p) {
  cg::grid_group grid = cg::this_grid();
  // 112 KB: gru acts [256][64] f32 (16384 f) | planeA [256][64]h (8192 f) |
  // planeB [256][32]h (4096 f). Reduce reuses first 24576 f. p5 uses first
  // 16384 f; p6 first 10240 f (reduce 8192 f).
  __shared__ float sm[28672];
  unsigned ep = 0;

  // ---- prologue (4 slow cg syncs flush prologue's normal stores) ----
  if (blockIdx.x == 0) {
    for (int i = threadIdx.x; i < 1024; i += 512) p.bar[i] = 0u;
  }
  if (threadIdx.x < 64) {  // z transpose -> h1 region (consumed pre-overwrite)
    int i = blockIdx.x * 64 + threadIdx.x;
    int m = i >> 8, l = i & 255;
    p.h1[l * 64 + m] = p.z[i];
  }
  matmat<1024, 1024, 8>(p.Wv, p.Wo, p.part);            // Wvo (fp32 temp)
  vecmat(p.bh, p.w1, p.b1, p.bhw1, 256, 1024, 0, 2);
  vecmat(p.bv, p.Wo, p.bo, p.bvo, 1024, 1024, 2, 2);
  cvt_copy(p.Whh0, p.Whh0h, 786432);                    // raw weights -> fp16
  cvt_copy(p.Wih1, p.Wih1h, 786432);
  cvt_copy(p.Whh1, p.Whh1h, 786432);
  cvt_copy(p.w2,   p.w2h,   262144);
  cvt_copy(p.Wh,   p.Whh,   65536);
  grid.sync();
  matmat<1024, 3072, 24>(p.part, p.Wih0, p.Wvoihh);     // Wvoih -> fp16 direct
  matmat<256, 1024, 8>(p.Wh, p.w1, p.WhW1h);            // WhW1 -> fp16 direct
  vecmat(p.bvo, p.Wih0, p.bih0, p.bfold, 1024, 3072, 0, 6);
  grid.sync();
  gemv1024(p.h1, p.w1, p.b1, 256, 1, p.t1, nullptr, nullptr, sm);
  grid.sync();
  gemv1024(p.t1, p.w2, p.b2, 1024, 0, p.h1, p.h2, p.gin, sm);
  grid.sync();

  // ---- time loop: 8 fence-free phases/step ----
  for (int t = 0; t < TSTEP; ++t) {
    gru_mm(p.Wvoihh, p.gin, p.Whh0h, p.h1, p.part, sm); fastbar(p.bar, ep);
    gru_comb(p.part, p.bfold, p.bhh0, p.h1);            fastbar(p.bar, ep);
    gru_mm(p.Wih1h, p.h1, p.Whh1h, p.h2, p.part, sm);   fastbar(p.bar, ep);
    gru_comb(p.part, p.bih1, p.bhh1, p.h2);             fastbar(p.bar, ep);
    p5_mm(p.WhW1h, p.Whh, p.h2, p.part, sm);            fastbar(p.bar, ep);
    p5b(p.part, p.bhw1, p.bh, p.t1, p.out, t);          fastbar(p.bar, ep);
    p6_mm(p.w2h, p.t1, p.part, sm);                     fastbar(p.bar, ep);
    p6b(p.part, p.b2, p.gin);                           fastbar(p.bar, ep);
  }
}

// ---------------------------------------------------------------------------
// Fallback path (round-2 verified multi-kernel, fp32 — unchanged).
// ---------------------------------------------------------------------------
__global__ void fb_transpose(const float* __restrict__ z, float* __restrict__ zT) {
  int i = blockIdx.x * 256 + threadIdx.x;
  int m = i >> 8, l = i & 255;
  zT[l * 64 + m] = z[i];
}
__global__ void fb_copy2(const float* __restrict__ s, float* __restrict__ d1,
                         float* __restrict__ d2) {
  int i = blockIdx.x * 256 + threadIdx.x;
  float v = s[i]; d1[i] = v; d2[i] = v;
}
template <int ACT>
__global__ void fb_gemm(const float* __restrict__ A_T, const float* __restrict__ W,
                        const float* __restrict__ bias, float* __restrict__ C_T,
                        int K, int N, float* __restrict__ outp, int tstep) {
  const int m = threadIdx.x & 63;
  const int wv = threadIdx.x >> 6;
  const int c = blockIdx.x * 4 + wv;
  float acc0 = 0.f, acc1 = 0.f;
  const float* ap = A_T + m;
  const float* wp = W + c;
#pragma unroll 4
  for (int k = 0; k + 1 < K; k += 2) {
    acc0 = fmaf(ap[k * 64], wp[(size_t)k * N], acc0);
    acc1 = fmaf(ap[(k + 1) * 64], wp[(size_t)(k + 1) * N], acc1);
  }
  float v0 = acc0 + acc1 + bias[c];
  if (ACT) v0 = fmaxf(v0, 0.f);
  C_T[c * 64 + m] = v0;
  if (outp != nullptr) outp[(size_t)(m * TSTEP + tstep) * LATD + c] = v0;
}
__global__ void fb_gru(const float* __restrict__ xT, const float* __restrict__ hT,
                       const float* __restrict__ Wih, const float* __restrict__ Whh,
                       const float* __restrict__ bih, const float* __restrict__ bhh,
                       float* __restrict__ hnT) {
  const int m = threadIdx.x & 63;
  const int wv = threadIdx.x >> 6;
  const int c = blockIdx.x * 4 + wv;
  float racc = 0, zacc = 0, iacc = 0, nacc = 0;
  const float* xp = xT + m;
  const float* hp = hT + m;
  const float* wi = Wih + c;
  const float* wh = Whh + c;
#pragma unroll 2
  for (int k = 0; k < 1024; ++k) {
    float a = xp[k * 64];
    float h = hp[k * 64];
    const float* wik = wi + (size_t)k * 3072;
    const float* whk = wh + (size_t)k * 3072;
    racc = fmaf(a, wik[0], racc); racc = fmaf(h, whk[0], racc);
    zacc = fmaf(a, wik[1024], zacc); zacc = fmaf(h, whk[1024], zacc);
    iacc = fmaf(a, wik[2048], iacc);
    nacc = fmaf(h, whk[2048], nacc);
  }
  float r = 1.f / (1.f + expf(-(racc + bih[c] + bhh[c])));
  float zg = 1.f / (1.f + expf(-(zacc + bih[1024 + c] + bhh[1024 + c])));
  float nn = tanhf(iacc + bih[2048 + c] + r * (nacc + bhh[2048 + c]));
  hnT[c * 64 + m] = (1.f - zg) * nn + zg * hT[c * 64 + m];
}

extern "C" void kernel_launch(void* const* d_in, const int* in_sizes, int n_in,
                              void* d_out, int out_size, void* d_ws, size_t ws_size,
                              hipStream_t stream) {
  const float* z_start = (const float*)d_in[0];
  const float* w1 = (const float*)d_in[2];
  const float* b1 = (const float*)d_in[3];
  const float* w2 = (const float*)d_in[4];
  const float* b2 = (const float*)d_in[5];
  const float* Wv = (const float*)d_in[10];
  const float* bv = (const float*)d_in[11];
  const float* Wo = (const float*)d_in[12];
  const float* bo = (const float*)d_in[13];
  const float* Wih0 = (const float*)d_in[14];
  const float* Whh0 = (const float*)d_in[15];
  const float* bih0 = (const float*)d_in[16];
  const float* bhh0 = (const float*)d_in[17];
  const float* Wih1 = (const float*)d_in[18];
  const float* Whh1 = (const float*)d_in[19];
  const float* bih1 = (const float*)d_in[20];
  const float* bhh1 = (const float*)d_in[21];
  const float* Wh = (const float*)d_in[22];
  const float* bh = (const float*)d_in[23];
  float* out = (float*)d_out;
  float* ws = (float*)d_ws;

  // floats: 4x1572864 (Wvoih_h,Whh0_h,Wih1_h,Whh1_h) + part 1572864 +
  // 524288x2 (WhW1_h,w2_h) + 131072 (Wh_h) + 4x65536 acts + 5120 small + 1024
  const size_t need = (size_t)9312256 * 4;
  if (ws_size >= need) {
    P p;
    p.z = z_start; p.w1 = w1; p.b1 = b1; p.w2 = w2; p.b2 = b2;
    p.Wv = Wv; p.bv = bv; p.Wo = Wo; p.bo = bo;
    p.Wih0 = Wih0; p.Whh0 = Whh0; p.bih0 = bih0; p.bhh0 = bhh0;
    p.Wih1 = Wih1; p.Whh1 = Whh1; p.bih1 = bih1; p.bhh1 = bhh1;
    p.Wh = Wh; p.bh = bh; p.out = out;
    float* q = ws;
    p.Wvoihh = (__half*)q; q += 1572864;   // 1024x3072 halves
    p.Whh0h  = (__half*)q; q += 1572864;
    p.Wih1h  = (__half*)q; q += 1572864;
    p.Whh1h  = (__half*)q; q += 1572864;
    p.WhW1h  = (__half*)q; q += 524288;    // 1024x1024 halves
    p.Whh    = (__half*)q; q += 131072;    // 1024x256 halves
    p.w2h    = (__half*)q; q += 524288;
    p.part = q; q += 1572864;   // Wvo fp32 temp in prologue; partials in loop
    p.gin = q; q += 65536;
    p.h1 = q; q += 65536;       // also zT during prologue
    p.h2 = q; q += 65536;
    p.t1 = q; q += 65536;
    p.bvo = q; q += 1024;
    p.bfold = q; q += 3072;
    p.bhw1 = q; q += 1024;
    p.bar = (unsigned*)q; q += 1024;
    void* args[] = { &p };
    hipError_t e = hipLaunchCooperativeKernel((const void*)persist, dim3(256),
                                              dim3(512), args, 0, stream);
    if (e == hipSuccess) return;
  }

  // -------- fallback: verified round-2 path --------
  float* zsT = ws;
  float* vT = zsT + 16384;
  float* xaT = vT + 65536;
  float* t1T = xaT + 65536;
  float* ginT = t1T + 65536;
  float* nzT = ginT + 65536;
  float* h1T = nzT + 16384;
  float* h2T = h1T + 2 * 65536;

  fb_transpose<<<64, 256, 0, stream>>>(z_start, zsT);
  fb_gemm<1><<<256, 256, 0, stream>>>(zsT, w1, b1, t1T, 256, 1024, nullptr, 0);
  fb_gemm<0><<<256, 256, 0, stream>>>(t1T, w2, b2, h1T, 1024, 1024, nullptr, 0);
  fb_copy2<<<256, 256, 0, stream>>>(h1T, h2T, ginT);
  for (int t = 0; t < TSTEP; ++t) {
    float* h1p = h1T + (t & 1) * 65536;
    float* h1n = h1T + ((t + 1) & 1) * 65536;
    float* h2p = h2T + (t & 1) * 65536;
    float* h2n = h2T + ((t + 1) & 1) * 65536;
    fb_gemm<0><<<256, 256, 0, stream>>>(ginT, Wv, bv, vT, 1024, 1024, nullptr, 0);
    fb_gemm<0><<<256, 256, 0, stream>>>(vT, Wo, bo, xaT, 1024, 1024, nullptr, 0);
    fb_gru<<<256, 256, 0, stream>>>(xaT, h1p, Wih0, Whh0, bih0, bhh0, h1n);
    fb_gru<<<256, 256, 0, stream>>>(h1n, h2p, Wih1, Whh1, bih1, bhh1, h2n);
    fb_gemm<0><<<64, 256, 0, stream>>>(h2n, Wh, bh, nzT, 1024, 256, out, t);
    fb_gemm<1><<<256, 256, 0, stream>>>(nzT, w1, b1, t1T, 256, 1024, nullptr, 0);
    fb_gemm<1><<<256, 256, 0, stream>>>(t1T, w2, b2, ginT, 1024, 1024, nullptr, 0);
  }
}